// Round 11
// baseline (1184.343 us; speedup 1.0000x reference)
//
#include <hip/hip_runtime.h>
#include <math.h>

// Problem dims
#define TB 16   // batch (tasks)
#define TT 16   // train steps
#define LL 128  // test length
#define XX 256  // x dim
#define HH 512  // hidden
#define YY 256  // y dim

#define PW 588  // phase-2 act row pitch (>= 576, %4==0, %32==12 -> bank spread)

typedef unsigned long long u64;

// ---------------------------------------------------------------------------
// Cross-block communication primitives.
// WRITES: agent-scope atomic exchange, RETURNING variant (old value consumed
//   by an asm sink). vmcnt then counts the full round trip to the coherent
//   point, so the pre-arrive __syncthreads (vmcnt 0) guarantees completion
//   BEFORE the barrier fetch_add issues. (No-return atomics can retire vmcnt
//   early -> the R8-R10 rare stale reads.)
// READS: agent-scope atomic loads (bypass L1/L2 -> coherent point).
// ---------------------------------------------------------------------------
__device__ __forceinline__ void axg(float* p, float v) {
    float old = __hip_atomic_exchange(p, v, __ATOMIC_RELAXED, __HIP_MEMORY_SCOPE_AGENT);
    asm volatile("" :: "v"(old));   // keep old live -> returning opcode
}
__device__ __forceinline__ float ald(const float* p) {
    return __hip_atomic_load(p, __ATOMIC_RELAXED, __HIP_MEMORY_SCOPE_AGENT);
}
__device__ __forceinline__ u64 ald8(const u64* p) {
    return __hip_atomic_load(p, __ATOMIC_RELAXED, __HIP_MEMORY_SCOPE_AGENT);
}

// ---------------------------------------------------------------------------
// Counter-poll barrier (16 blocks/task): arrive = fetch_add on tb[0];
// waiters poll the counter itself. Monotonic. __syncthreads before arrive
// drains vmcnt for all waves (returning-exchange responses received).
// ---------------------------------------------------------------------------
__device__ __forceinline__ void barrier_arrive(unsigned* tb) {
    __hip_atomic_fetch_add(&tb[0], 1u, __ATOMIC_RELAXED, __HIP_MEMORY_SCOPE_AGENT);
}
__device__ __forceinline__ void barrier_wait(unsigned* tb, unsigned n) {
    while (__hip_atomic_load(&tb[0], __ATOMIC_RELAXED,
                             __HIP_MEMORY_SCOPE_AGENT) < n * 16u)
        __builtin_amdgcn_s_sleep(1);
}

// Sum 16 per-block partials -> s_c[s] = lr*(c[s]+plus1). 64-bit atomic loads.
__device__ __forceinline__ void cload(const float* crd, float plus1, float lr,
                                      float* s_c) {
    const int tid = threadIdx.x;
    if (tid < 128) {
        const int s = tid >> 3, j = tid & 7;
        const u64 u = ald8((const u64*)(crd + s * 16) + j);
        float v = __uint_as_float((unsigned)(u & 0xffffffffu)) +
                  __uint_as_float((unsigned)(u >> 32));
        v += __shfl_xor(v, 1);
        v += __shfl_xor(v, 2);
        v += __shfl_xor(v, 4);
        if (j == 0) s_c[s] = lr * (v + plus1);
    }
}

// Partial dots of fresh slice (sout) against own LDS history rows s <= tmax.
__device__ __forceinline__ void partials32L(const float* hist, int tmax,
                                            float* cpw, int blk, const float* sout) {
    const int tid = threadIdx.x;
    const int s2 = tid >> 4, i = tid & 15;
    float pp = 0.f;
    const bool act = (s2 <= tmax);
    if (act) {
        pp = hist[s2 * 32 + 2 * i] * sout[2 * i] +
             hist[s2 * 32 + 2 * i + 1] * sout[2 * i + 1];
    }
    pp += __shfl_xor(pp, 1);
    pp += __shfl_xor(pp, 2);
    pp += __shfl_xor(pp, 4);
    pp += __shfl_xor(pp, 8);
    if (act && i == 0) axg(&cpw[s2 * 16 + blk], pp);
}

__device__ __forceinline__ void partials16L(const float* hist, int tmax,
                                            float* cpw, int blk, const float* sout) {
    const int tid = threadIdx.x;
    const int s2 = tid >> 4, i = tid & 15;
    float pp = 0.f;
    const bool act = (s2 <= tmax);
    if (act) pp = hist[s2 * 16 + i] * sout[i];
    pp += __shfl_xor(pp, 1);
    pp += __shfl_xor(pp, 2);
    pp += __shfl_xor(pp, 4);
    pp += __shfl_xor(pp, 8);
    if (act && i == 0) axg(&cpw[s2 * 16 + blk], pp);
}

// ---------------------------------------------------------------------------
// One phase-1 stage. MODE: 0=F2 1=F3 2=F4 3=B4 4=B3 5=B2(+h1_{t+1}).
// Weight slice prefetched to REGISTERS before the barrier wait; history in
// LDS; fresh vector + coefficient partials via agent atomics (IF).
// ---------------------------------------------------------------------------
template <int MODE>
__device__ __forceinline__ void do_stage(
    int t, unsigned n, float lr, int base, int base16, int blk,
    const float* __restrict__ M, const float* __restrict__ src,
    float* __restrict__ dst, float* __restrict__ dst2,
    const float* __restrict__ tyb, const float* __restrict__ tgb, float rbias,
    unsigned* __restrict__ tb, float* __restrict__ cw, float* __restrict__ crd,
    float* s_v, float* sp, float* sout, float* s_c,
    float* hcorr, float* hpart, float* hself,
    float* hD1v, float* hZ1v, float* sG1v)
{
    const int tid = threadIdx.x;
    constexpr int ROWS = (MODE == 2) ? 16 : 32;
    constexpr int G = 256 / ROWS;
    constexpr int KTOT = (MODE == 3) ? 256 : 512;
    constexpr int KPG = KTOT / G;
    constexpr int LD = (MODE == 2) ? YY : HH;

    const int r = tid & (ROWS - 1);
    const int j = tid / ROWS;

    // ---- weight prefetch (before barrier; overlaps the wait) ----
    const float* col = M + (j * KPG) * LD + r;
    float wreg[KPG];
    #pragma unroll
    for (int k = 0; k < KPG; ++k) wreg[k] = col[k * LD];

    // ---- wait for previous stage (all 16 blocks) ----
    if (tid == 0) barrier_wait(tb, n);
    __syncthreads();

    // ---- stage fresh vector + coefficients (IF reads, parallel) ----
    constexpr float P1 = (MODE == 0 || MODE == 1) ? 1.0f : 0.0f;
    cload(crd, P1, lr, s_c);
    constexpr int NF = (MODE == 3) ? YY : HH;
    if (tid < (NF >> 1)) ((u64*)s_v)[tid] = ald8((const u64*)src + tid);
    __syncthreads();

    // ---- matvec: registers x LDS ----
    float a = 0.f;
    const float* vv = s_v + j * KPG;
    #pragma unroll
    for (int k = 0; k < KPG; ++k) a += wreg[k] * vv[k];
    const int lane = tid & 63, w = tid >> 6;
    float sres = 0.f;
    if constexpr (ROWS == 32) {
        a += __shfl_xor(a, 32);
        if (lane < 32) sp[w * 32 + lane] = a;
        __syncthreads();
        if (tid < 32) sres = sp[tid] + sp[32 + tid] + sp[64 + tid] + sp[96 + tid];
    } else {
        a += __shfl_xor(a, 16);
        a += __shfl_xor(a, 32);
        if (lane < 16) sp[w * 16 + lane] = a;
        __syncthreads();
        if (tid < 16) sres = sp[tid] + sp[16 + tid] + sp[32 + tid] + sp[48 + tid];
    }

    // ---- epilogue (LDS history only) ----
    if (tid < ROWS) {
        float corr = 0.f;
        for (int s = 0; s < t; ++s) corr += hcorr[s * ROWS + tid] * s_c[s];
        if constexpr (MODE == 5) {
            const float dz = (sres - corr) * ((hcorr[t * 32 + tid] > 0.f) ? 1.f : 0.f);
            axg(dst + t * HH + base + tid, dz);
            hD1v[t * 32 + tid] = dz;
            if (t + 1 < TT) {
                float cr = dz * sG1v[t * 16 + (t + 1)];
                for (int s = 0; s < t; ++s)
                    cr += hD1v[s * 32 + tid] * sG1v[s * 16 + (t + 1)];
                const float h1n = fmaxf(hZ1v[(t + 1) * 32 + tid] - lr * cr, 0.f);
                axg(dst2 + (t + 1) * HH + base + tid, h1n);
                hself[(t + 1) * 32 + tid] = h1n;
                sout[tid] = h1n;
            }
        } else {
            float v;
            if constexpr (MODE == 0)
                v = fmaxf(sres + rbias - corr, 0.f);
            else if constexpr (MODE == 1)
                v = fmaxf(sres + rbias - corr, 0.f) * tgb[t * HH + base + tid];
            else if constexpr (MODE == 2)
                v = (sres - corr - tyb[t * YY + base16 + tid]) * (2.0f / YY);
            else if constexpr (MODE == 3)
                v = (sres - corr) * tgb[t * HH + base + tid] *
                    ((hcorr[t * 32 + tid] > 0.f) ? 1.f : 0.f);
            else
                v = (sres - corr) * ((hcorr[t * 32 + tid] > 0.f) ? 1.f : 0.f);
            if constexpr (MODE == 2) axg(dst + t * YY + base16 + tid, v);
            else                     axg(dst + t * HH + base + tid, v);
            hself[t * ROWS + tid] = v;
            sout[tid] = v;
        }
    }
    __syncthreads();

    // ---- partials for next stage's coefficients ----
    const int tmax = (MODE == 5) ? ((t + 1 < TT) ? t : -1) : (t - 1);
    if constexpr (MODE == 2) partials16L(hpart, tmax, cw, blk, sout);
    else                     partials32L(hpart, tmax, cw, blk, sout);
    __syncthreads();   // drains exchange responses (all waves)
    if (tid == 0) barrier_arrive(tb);
}

// ---------------------------------------------------------------------------
// Transpose W1..W4 (64x64 tiles), zero barrier flags, write inner_lr output.
// ---------------------------------------------------------------------------
__global__ __launch_bounds__(256) void k_tr(
    const float* __restrict__ W1, const float* __restrict__ W2,
    const float* __restrict__ W3, const float* __restrict__ W4,
    float* __restrict__ WT1, float* __restrict__ WT2,
    float* __restrict__ WT3, float* __restrict__ WT4,
    const float* __restrict__ loglr, float* __restrict__ out,
    unsigned* __restrict__ bars)
{
    const int tid = threadIdx.x;
    int bid = blockIdx.x;
    if (blockIdx.x == 0) {
        unsigned old = __hip_atomic_exchange(&bars[tid], 0u, __ATOMIC_RELAXED,
                                             __HIP_MEMORY_SCOPE_AGENT);
        asm volatile("" :: "v"(old));
    }
    if (blockIdx.x == 0 && tid == 0) out[2048] = expf(loglr[0]);

    const float* src; float* dst; int R, C;
    if (bid < 32)       { src = W1; dst = WT1; R = 512; C = 256; }
    else if (bid < 96)  { src = W2; dst = WT2; R = 512; C = 512; bid -= 32; }
    else if (bid < 160) { src = W3; dst = WT3; R = 512; C = 512; bid -= 96; }
    else                { src = W4; dst = WT4; R = 256; C = 512; bid -= 160; }
    const int tilesC = C >> 6;
    const int i0 = (bid / tilesC) * 64, j0 = (bid % tilesC) * 64;

    __shared__ float sm[64][65];
    #pragma unroll
    for (int rep = 0; rep < 16; ++rep) {
        const int flat = rep * 256 + tid;
        const int r = flat >> 6, c = flat & 63;
        sm[r][c] = src[(i0 + r) * C + j0 + c];
    }
    __syncthreads();
    #pragma unroll
    for (int rep = 0; rep < 16; ++rep) {
        const int flat = rep * 256 + tid;
        const int c = flat >> 6, r = flat & 63;
        dst[(j0 + c) * R + i0 + r] = sm[r][c];
    }
}

// ---------------------------------------------------------------------------
// Persistent inner loop. 256 blocks of 256; 16 blocks/task, 32 rows/block.
// ---------------------------------------------------------------------------
__global__ __launch_bounds__(256, 1) void k_inner(
    const float* __restrict__ tx, const float* __restrict__ ty, const float* __restrict__ tg,
    const float* __restrict__ b1v, const float* __restrict__ b2v, const float* __restrict__ b3v,
    const float* __restrict__ W2, const float* __restrict__ W3, const float* __restrict__ W4,
    const float* __restrict__ WT1, const float* __restrict__ WT2, const float* __restrict__ WT3,
    const float* __restrict__ WT4, const float* __restrict__ loglr,
    float* __restrict__ H1, float* __restrict__ H2, float* __restrict__ HG,
    float* __restrict__ D1, float* __restrict__ D2, float* __restrict__ D3, float* __restrict__ D4,
    float* __restrict__ cpart, unsigned* __restrict__ bars)
{
    const int tid = threadIdx.x;
    const int lane = tid & 63, w = tid >> 6;
    const int g = blockIdx.x;
    const int b = g >> 4;
    const int blk = ((g & 7) << 1) | ((g >> 3) & 1);   // XCD-local weight rows
    const int base = blk * 32, base16 = blk * 16;
    const float lr = expf(loglr[0]);
    unsigned* tb = bars + b * 16;

    const float* txb = tx + b * (TT * XX);
    const float* tyb = ty + b * (TT * YY);
    const float* tgb = tg + b * (TT * HH);
    float* H1b = H1 + b * (TT * HH);
    float* H2b = H2 + b * (TT * HH);
    float* HGb = HG + b * (TT * HH);
    float* D1b = D1 + b * (TT * HH);
    float* D2b = D2 + b * (TT * HH);
    float* D3b = D3 + b * (TT * HH);
    float* D4b = D4 + b * (TT * YY);
    float* cw  = cpart + b * 256;          // parity-0 partial buffer [16 s][16 blk]
    float* crd = cpart + 4096 + b * 256;   // parity-1

    __shared__ float s_x[16 * 260];  // P0 only
    __shared__ float spz[2176];      // P0 only
    __shared__ __align__(16) float s_v[HH];
    __shared__ float sp[128];
    __shared__ float sout[32];
    __shared__ float s_c[16];
    // Block-private history (own 32/16-row slices), LDS-resident:
    __shared__ float hH1[TT * 32], hH2[TT * 32], hHG[TT * 32];
    __shared__ float hD1[TT * 32], hD2[TT * 32], hD3[TT * 32];
    __shared__ float hD4[TT * 16];
    __shared__ float hZ1[TT * 32];
    __shared__ float sG1[TT * 16];

    const float rb2 = (tid < 32) ? b2v[base + tid] : 0.f;
    const float rb3 = (tid < 32) ? b3v[base + tid] : 0.f;

    // ---------------- P0: Z1base (LDS), G1 (LDS, replicated), H1[0] ----------
    {
        const float4* src4 = (const float4*)txb;   // 1024 float4
        #pragma unroll
        for (int q = 0; q < 4; ++q) {
            const int idx = q * 256 + tid;
            const int tt = idx >> 6, k4 = idx & 63;
            *(float4*)&s_x[tt * 260 + k4 * 4] = src4[idx];
        }
    }
    __syncthreads();
    {
        const int r = tid & 31, j = tid >> 5;
        float acc[16];
        #pragma unroll
        for (int tt = 0; tt < 16; ++tt) acc[tt] = 0.f;
        const float* col = WT1 + (j * 32) * HH + base + r;
        #pragma unroll 4
        for (int kk = 0; kk < 32; ++kk) {
            const float wv = col[kk * HH];
            const int k = j * 32 + kk;
            #pragma unroll
            for (int tt = 0; tt < 16; ++tt) acc[tt] += wv * s_x[tt * 260 + k];
        }
        #pragma unroll
        for (int tt = 0; tt < 16; ++tt) {
            float a = acc[tt] + __shfl_xor(acc[tt], 32);
            if (lane < 32) spz[w * 544 + lane * 17 + tt] = a;
        }
        __syncthreads();
        const int rr = tid & 31, tp = tid >> 5;
        #pragma unroll
        for (int q = 0; q < 2; ++q) {
            const int tt = tp * 2 + q;
            const int row = base + rr;
            float v = spz[rr * 17 + tt] + spz[544 + rr * 17 + tt] +
                      spz[1088 + rr * 17 + tt] + spz[1632 + rr * 17 + tt];
            v += b1v[row];
            hZ1[tt * 32 + rr] = v;
            if (tt == 0) {
                const float h = fmaxf(v, 0.f);
                hH1[rr] = h;
                axg(&H1b[row], h);
            }
        }
    }
    {   // Gram matrix, replicated per block
        const int ss = tid >> 4, uu = tid & 15;
        float a = 0.f;
        for (int k = 0; k < 256; ++k) a += s_x[ss * 260 + k] * s_x[uu * 260 + k];
        sG1[ss * 16 + uu] = a + 1.0f;
    }
    __syncthreads();   // drains exchange responses + orders LDS writes
    if (tid == 0) barrier_arrive(tb);

    // ---------------- Phase 1: 16 SGD steps x 6 stages ----------------
    unsigned n = 1;
    #pragma unroll 1
    for (int t = 0; t < TT; ++t) {
        do_stage<0>(t, n++, lr, base, base16, blk, WT2 + base, H1b + t * HH,
                    H2b, nullptr, tyb, tgb, rb2, tb, cw, crd,
                    s_v, sp, sout, s_c, hD2, hH2, hH2, hD1, hZ1, sG1);
        { float* tmp = cw; cw = crd; crd = tmp; }
        do_stage<1>(t, n++, lr, base, base16, blk, WT3 + base, H2b + t * HH,
                    HGb, nullptr, tyb, tgb, rb3, tb, cw, crd,
                    s_v, sp, sout, s_c, hD3, hHG, hHG, hD1, hZ1, sG1);
        { float* tmp = cw; cw = crd; crd = tmp; }
        do_stage<2>(t, n++, lr, base, base16, blk, WT4 + base16, HGb + t * HH,
                    D4b, nullptr, tyb, tgb, 0.f, tb, cw, crd,
                    s_v, sp, sout, s_c, hD4, hD4, hD4, hD1, hZ1, sG1);
        { float* tmp = cw; cw = crd; crd = tmp; }
        do_stage<3>(t, n++, lr, base, base16, blk, W4 + base, D4b + t * YY,
                    D3b, nullptr, tyb, tgb, 0.f, tb, cw, crd,
                    s_v, sp, sout, s_c, hHG, hD3, hD3, hD1, hZ1, sG1);
        { float* tmp = cw; cw = crd; crd = tmp; }
        do_stage<4>(t, n++, lr, base, base16, blk, W3 + base, D3b + t * HH,
                    D2b, nullptr, tyb, tgb, 0.f, tb, cw, crd,
                    s_v, sp, sout, s_c, hH2, hD2, hD2, hD1, hZ1, sG1);
        { float* tmp = cw; cw = crd; crd = tmp; }
        do_stage<5>(t, n++, lr, base, base16, blk, W2 + base, D2b + t * HH,
                    D1b, H1b, tyb, tgb, 0.f, tb, cw, crd,
                    s_v, sp, sout, s_c, hH1, hH1, hH1, hD1, hZ1, sG1);
        { float* tmp = cw; cw = crd; crd = tmp; }
    }
}

// ---------------------------------------------------------------------------
// Phase-2 fused layer (per block: 8 test rows, all OUT columns). Runs in its
// own dispatch after k_inner. ALL reads of k_inner-produced arrays (Asrc
// history, Dj correction rows) use agent-scope atomic loads: k_inner's
// exchanges update the coherent point WITHOUT invalidating L2 lines cached by
// a PREVIOUS graph replay's k_p2 — normal loads could hit those stale lines
// (the replay-only divergence). Weights/bias/inputs are host-written ->
// normal loads fine.
// out[l][n] = post( sum_k WT[k][n]*act[l][k] + sum_s Dj[s][n]*(-lr*ip[s][l]) )
// via extended-K. 512 threads: 32 r-lanes x 16 j-groups; 2 n x 8 l per
// thread; 16-way sP reduce. No runtime-indexed register arrays (rule #20).
// ---------------------------------------------------------------------------
template <int K, int OUT, bool RELU, bool BIAS, bool PLUSONE>
__device__ __forceinline__ void p2_layer(
    const float* __restrict__ WT,      // [K][OUT]
    const float* __restrict__ bias,    // [OUT] or null
    const float* __restrict__ Dj,      // [16][OUT]  (k_inner output)
    const float* __restrict__ Asrc,    // [16][K]    (k_inner output / input)
    float lr, float* sact, float* sactN, float* sWA)
{
    constexpr int KE = (K + 16 + 63) & ~63;   // 320 / 576
    constexpr int KPG = KE / 16;              // 20 / 36 (multiple of 4)
    constexpr int SAP = K + 4;                // sA pitch (bank spread)
    const int tid = threadIdx.x;

    // ---- stage A rows into LDS (coherent 64-bit atomic loads) ----
    float* sA = sWA;   // [16][SAP]
    {
        constexpr int KH = K / 2;
        for (int i = tid; i < 16 * KH; i += 512) {
            const int s = i / KH, c = i - s * KH;
            *(u64*)(sA + s * SAP + c * 2) =
                ald8((const u64*)(Asrc + (long)s * K) + c);
        }
    }
    __syncthreads();

    // ---- ip[s][l] -> sact[l][K+s] = -lr*(A_s . act_l + plus1) ----
    {
        const int s = tid >> 5, lq = tid & 31;
        const int l = lq >> 2, q = lq & 3;
        const float4* av = (const float4*)(sA + s * SAP + q * (K / 4));
        const float4* xv = (const float4*)(sact + l * PW + q * (K / 4));
        float a = 0.f;
        for (int k = 0; k < K / 16; ++k) {
            const float4 u = av[k], x = xv[k];
            a += u.x * x.x + u.y * x.y + u.z * x.z + u.w * x.w;
        }
        a += __shfl_xor(a, 1);
        a += __shfl_xor(a, 2);
        if (q == 0) sact[l * PW + K + s] = -lr * (a + (PLUSONE ? 1.f : 0.f));
    }
    __syncthreads();

    // ---- GEMM ----
    float* sP = sWA;   // [16][64][9] partials (sA dead after ip step)
    const int r = tid & 31, j = tid >> 5;    // j in 0..15
    const float* xb = sact + j * KPG;
    for (int nc = 0; nc < OUT / 64; ++nc) {
        const int n0 = nc * 64 + r;
        float a0[8], a1[8];
        #pragma unroll
        for (int l = 0; l < 8; ++l) { a0[l] = 0.f; a1[l] = 0.f; }
        if ((j + 1) * KPG <= K) {
            const float* c0 = WT + (long)(j * KPG) * OUT + n0;
            #pragma unroll 4
            for (int kk = 0; kk < KPG; kk += 4) {
                float w00, w01, w02, w03, w10, w11, w12, w13;
                w00 = c0[(long)(kk + 0) * OUT]; w10 = c0[(long)(kk + 0) * OUT + 32];
                w01 = c0[(long)(kk + 1) * OUT]; w11 = c0[(long)(kk + 1) * OUT + 32];
                w02 = c0[(long)(kk + 2) * OUT]; w12 = c0[(long)(kk + 2) * OUT + 32];
                w03 = c0[(long)(kk + 3) * OUT]; w13 = c0[(long)(kk + 3) * OUT + 32];
                #pragma unroll
                for (int l = 0; l < 8; ++l) {
                    const float4 x = *(const float4*)&xb[l * PW + kk];
                    a0[l] += w00 * x.x; a0[l] += w01 * x.y;
                    a0[l] += w02 * x.z; a0[l] += w03 * x.w;
                    a1[l] += w10 * x.x; a1[l] += w11 * x.y;
                    a1[l] += w12 * x.z; a1[l] += w13 * x.w;
                }
            }
        } else {
            #pragma unroll 4
            for (int kk = 0; kk < KPG; kk += 4) {
                float w0q[4], w1q[4];
                #pragma unroll
                for (int q = 0; q < 4; ++q) {
                    const int k = j * KPG + kk + q;
                    w0q[q] = (k < K) ? WT[(long)k * OUT + n0]
                           : (k < K + 16) ? ald(&Dj[(k - K) * OUT + n0]) : 0.f;
                    w1q[q] = (k < K) ? WT[(long)k * OUT + n0 + 32]
                           : (k < K + 16) ? ald(&Dj[(k - K) * OUT + n0 + 32]) : 0.f;
                }
                #pragma unroll
                for (int l = 0; l < 8; ++l) {
                    const float4 x = *(const float4*)&xb[l * PW + kk];
                    a0[l] += w0q[0] * x.x; a0[l] += w0q[1] * x.y;
                    a0[l] += w0q[2] * x.z; a0[l] += w0q[3] * x.w;
                    a1[l] += w1q[0] * x.x; a1[l] += w1q[1] * x.y;
                    a1[l] += w1q[2] * x.z; a1[l] += w1q[3] * x.w;
                }
            }
        }
        __syncthreads();   // sP region free (vs sA / previous reduce reads)
        #pragma unroll
        for (int l = 0; l < 8; ++l) {
            sP[(j * 64 + r) * 9 + l]      = a0[l];
            sP[(j * 64 + 32 + r) * 9 + l] = a1[l];
        }
        __syncthreads();
        {   // 16-way reduce: exactly one output per thread (64 n x 8 l = 512)
            const int nn = tid >> 3, ll = tid & 7;
            float v = 0.f;
            #pragma unroll
            for (int q = 0; q < 16; ++q) v += sP[(q * 64 + nn) * 9 + ll];
            const int n = nc * 64 + nn;
            if (BIAS) v += bias[n];
            if (RELU) v = fmaxf(v, 0.f);
            sactN[ll * PW + n] = v;
        }
    }
    __syncthreads();
    // zero-pad cols [OUT+16, PW) of the output for the next consumer
    constexpr int ZC = PW - (OUT + 16);
    for (int f = tid; f < 8 * ZC; f += 512) {
        const int l = f / ZC, c = f - l * ZC;
        sactN[l * PW + OUT + 16 + c] = 0.f;
    }
    __syncthreads();
}

// ---------------------------------------------------------------------------
// Phase-2: test forward + loss, fully block-local. grid 256 blocks of 512:
// block = (task b, 8 test rows). No cross-block communication.
// ---------------------------------------------------------------------------
__global__ __launch_bounds__(512, 1) void k_p2(
    const float* __restrict__ tx, const float* __restrict__ tex,
    const float* __restrict__ tey, const float* __restrict__ teg,
    const float* __restrict__ b1v, const float* __restrict__ b2v,
    const float* __restrict__ b3v,
    const float* __restrict__ WT1, const float* __restrict__ WT2,
    const float* __restrict__ WT3, const float* __restrict__ WT4,
    const float* __restrict__ H1, const float* __restrict__ H2,
    const float* __restrict__ HG,
    const float* __restrict__ D1, const float* __restrict__ D2,
    const float* __restrict__ D3, const float* __restrict__ D4,
    const float* __restrict__ loglr, float* __restrict__ outp)
{
    const int tid = threadIdx.x;
    const int b = blockIdx.x >> 4;
    const int l0 = (blockIdx.x & 15) * 8;
    const float lr = expf(loglr[0]);

    __shared__ __align__(16) float pool[18624];   // ~74.5 KB
    float* a0  = pool;            // act buffers [8][PW]
    float* a1  = pool + 4704;     // 8*588
    float* sWA = pool + 9408;     // scratch: sA [16][K+4] / sP [16][64][9]

    const float* txb = tx + b * (TT * XX);
    const float* H1b = H1 + b * (TT * HH);
    const float* H2b = H2 + b * (TT * HH);
    const float* HGb = HG + b * (TT * HH);
    const float* D1b = D1 + b * (TT * HH);
    const float* D2b = D2 + b * (TT * HH);
    const float* D3b = D3 + b * (TT * HH);
    const float* D4b = D4 + b * (TT * YY);

    // stage tex rows (zero-padded to PW)
    for (int f = tid; f < 8 * PW; f += 512) {
        const int l = f / PW, c = f - l * PW;
        a0[f] = (c < XX) ? tex[((long)b * LL + l0 + l) * XX + c] : 0.f;
    }
    __syncthreads();

    p2_layer<XX, HH, true, true, true>(WT1, b1v, D1b, txb, lr, a0, a1, sWA);
    p2_layer<HH, HH, true, true, true>(WT2, b2v, D2b, H1b, lr, a1, a0, sWA);
    p2_layer<HH, HH, true, true, true>(WT3, b3v, D3b, H2b, lr, a0, a1, sWA);

    // gate act3 with test_gate
    for (int f = tid; f < 8 * HH; f += 512) {
        const int l = f >> 9, k = f & 511;
        a1[l * PW + k] *= teg[((long)b * LL + l0 + l) * HH + k];
    }
    __syncthreads();

    p2_layer<HH, YY, false, false, false>(WT4, nullptr, D4b, HGb, lr, a1, a0, sWA);

    // logits out
    for (int f = tid; f < 8 * YY; f += 512) {
        const int l = f >> 8, y = f & 255;
        outp[4097 + ((long)(b * LL + l0 + l)) * YY + y] = a0[l * PW + y];
    }
    // loss + evaluation (first 256 threads: 8 l x 32 lanes)
    if (tid < 256) {
        const int l = tid >> 5, kk = tid & 31;
        float a = 0.f;
        #pragma unroll
        for (int jj = 0; jj < 8; ++jj) {
            const int y = kk * 8 + jj;
            const float d = a0[l * PW + y] -
                            tey[((long)b * LL + l0 + l) * YY + y];
            a += d * d;
        }
        a += __shfl_xor(a, 1);
        a += __shfl_xor(a, 2);
        a += __shfl_xor(a, 4);
        a += __shfl_xor(a, 8);
        a += __shfl_xor(a, 16);
        if (kk == 0) {
            const float v = a * (1.0f / YY);
            const int idx = b * LL + l0 + l;
            outp[idx] = v;
            outp[2049 + idx] = v;
        }
    }
}

// ---------------------------------------------------------------------------
extern "C" void kernel_launch(void* const* d_in, const int* in_sizes, int n_in,
                              void* d_out, int out_size, void* d_ws, size_t ws_size,
                              hipStream_t stream)
{
    const float* tx    = (const float*)d_in[0];   // train_x  [B][T][X]
    const float* ty    = (const float*)d_in[1];   // train_y  [B][T][Y]
    const float* tex   = (const float*)d_in[2];   // test_x   [B][L][X]
    const float* tey   = (const float*)d_in[3];   // test_y   [B][L][Y]
    const float* tg    = (const float*)d_in[4];   // train_gate [B][T][H]
    const float* teg   = (const float*)d_in[5];   // test_gate  [B][L][H]
    const float* W1    = (const float*)d_in[6];
    const float* b1    = (const float*)d_in[7];
    const float* W2    = (const float*)d_in[8];
    const float* b2    = (const float*)d_in[9];
    const float* W3    = (const float*)d_in[10];
    const float* b3    = (const float*)d_in[11];
    const float* W4    = (const float*)d_in[12];
    const float* loglr = (const float*)d_in[13];

    float* out = (float*)d_out;
    float* ws  = (float*)d_ws;

    // workspace layout (floats)
    float* H1     = ws + 135168;        // 131072
    float* H2     = ws + 266240;        // 131072
    float* HG     = ws + 397312;        // 131072
    float* D1     = ws + 528384;        // 131072
    float* D2     = ws + 659456;        // 131072
    float* D3     = ws + 790528;        // 131072
    float* D4     = ws + 921600;        // 65536
    float* ActA   = ws + 1024000;       // holds WT1..WT4
    float* WT1    = ActA;               // [256][512] = 131072
    float* WT2    = ActA + 131072;      // [512][512] = 262144
    float* WT3    = ActA + 393216;      // [512][512] = 262144
    float* WT4    = ActA + 655360;      // [512][256] = 131072
    float* cpart  = ws + 3121152;       // 2 x [16 tasks][16 s][16 blk] = 8192
    unsigned* bars = (unsigned*)(ws + 3129344);  // 16 tasks x 16 uints

    // Transpose weights, zero barriers, emit inner_lr.
    k_tr<<<192, 256, 0, stream>>>(W1, W2, W3, W4, WT1, WT2, WT3, WT4, loglr, out, bars);

    // 16-step MAML inner loop (persistent; returning-exchange handoff).
    k_inner<<<TB * 16, 256, 0, stream>>>(tx, ty, tg, b1, b2, b3, W2, W3, W4,
                                         WT1, WT2, WT3, WT4, loglr,
                                         H1, H2, HG, D1, D2, D3, D4,
                                         cpart, bars);

    // Phase 2: test-set forward + loss, one block-local dispatch (512 thr).
    k_p2<<<TB * 16, 512, 0, stream>>>(tx, tex, tey, teg, b1, b2, b3,
                                      WT1, WT2, WT3, WT4,
                                      H1, H2, HG, D1, D2, D3, D4,
                                      loglr, out);
}

// Round 13
// 561.739 us; speedup vs baseline: 2.1084x; 2.1084x over previous
//
#include <hip/hip_runtime.h>
#include <math.h>

// Problem dims
#define TB 16   // batch (tasks)
#define TT 16   // train steps
#define LL 128  // test length
#define XX 256  // x dim
#define HH 512  // hidden
#define YY 256  // y dim

#define PW 588  // phase-2 act row pitch
#define SENTU 0xFFC0DEADu   // sentinel: NaN payload, never produced by finite math

typedef unsigned long long u64;

// ---------------------------------------------------------------------------
// Cross-block primitives (all agent-scope, coherent-point).
// WRITE: no-return atomic exchange — executes at the coherent point, no
//   response wait. Safe here because readers poll the DATA ITSELF (sentinel
//   protocol) — there is no separate flag whose ordering could race (the
//   R8-R10 bug). R11 proved returning exchanges correct but paid an HBM RT
//   per write on the serial chain; self-announcing data removes that.
// READ: atomic loads (bypass L1/L2).
// ---------------------------------------------------------------------------
__device__ __forceinline__ void axs(float* p, float v) {
    (void)__hip_atomic_exchange(p, v, __ATOMIC_RELAXED, __HIP_MEMORY_SCOPE_AGENT);
}
__device__ __forceinline__ float ald(const float* p) {
    return __hip_atomic_load(p, __ATOMIC_RELAXED, __HIP_MEMORY_SCOPE_AGENT);
}
__device__ __forceinline__ u64 ald8(const u64* p) {
    return __hip_atomic_load(p, __ATOMIC_RELAXED, __HIP_MEMORY_SCOPE_AGENT);
}
// Poll a word until it is no longer the sentinel; return its float value.
__device__ __forceinline__ float pollf(const float* p) {
    unsigned u = __hip_atomic_load((const unsigned*)p, __ATOMIC_RELAXED,
                                   __HIP_MEMORY_SCOPE_AGENT);
    while (u == SENTU) {
        __builtin_amdgcn_s_sleep(1);
        u = __hip_atomic_load((const unsigned*)p, __ATOMIC_RELAXED,
                              __HIP_MEMORY_SCOPE_AGENT);
    }
    return __uint_as_float(u);
}

// Poll+sum 16 per-block partials -> s_c[s] = lr*(c[s]+plus1) for s < cnt.
__device__ __forceinline__ void cload_poll(const float* crd, int cnt, float plus1,
                                           float lr, float* s_c) {
    const int tid = threadIdx.x;
    if (tid < 128) {
        const int s = tid >> 3, j = tid & 7;
        float v = 0.f;
        if (s < cnt) {
            const float lo = pollf(crd + s * 16 + 2 * j);
            const float hi = pollf(crd + s * 16 + 2 * j + 1);
            v = lo + hi;
        }
        v += __shfl_xor(v, 1);
        v += __shfl_xor(v, 2);
        v += __shfl_xor(v, 4);
        if (j == 0) s_c[s] = lr * (v + plus1);
    }
}

// Partial dots of fresh slice (sout) against own LDS history rows s <= tmax.
__device__ __forceinline__ void partials32L(const float* hist, int tmax,
                                            float* cpw, int blk, const float* sout) {
    const int tid = threadIdx.x;
    const int s2 = tid >> 4, i = tid & 15;
    float pp = 0.f;
    const bool act = (s2 <= tmax);
    if (act) {
        pp = hist[s2 * 32 + 2 * i] * sout[2 * i] +
             hist[s2 * 32 + 2 * i + 1] * sout[2 * i + 1];
    }
    pp += __shfl_xor(pp, 1);
    pp += __shfl_xor(pp, 2);
    pp += __shfl_xor(pp, 4);
    pp += __shfl_xor(pp, 8);
    if (act && i == 0) axs(&cpw[s2 * 16 + blk], pp);
}

__device__ __forceinline__ void partials16L(const float* hist, int tmax,
                                            float* cpw, int blk, const float* sout) {
    const int tid = threadIdx.x;
    const int s2 = tid >> 4, i = tid & 15;
    float pp = 0.f;
    const bool act = (s2 <= tmax);
    if (act) pp = hist[s2 * 16 + i] * sout[i];
    pp += __shfl_xor(pp, 1);
    pp += __shfl_xor(pp, 2);
    pp += __shfl_xor(pp, 4);
    pp += __shfl_xor(pp, 8);
    if (act && i == 0) axs(&cpw[s2 * 16 + blk], pp);
}

// ---------------------------------------------------------------------------
// One phase-1 stage. MODE: 0=F2 1=F3 2=F4 3=B4 4=B3 5=B2(+h1_{t+1}).
// NO barrier: readers poll sentinel-prefilled write-once buffers. Weight
// slice register-prefetched (overlaps the polls); history in LDS.
// cw = this stage's cpart region; crd = previous stage's (polled, s < t).
// ---------------------------------------------------------------------------
template <int MODE>
__device__ __forceinline__ void do_stage(
    int t, float lr, int base, int base16, int blk,
    const float* __restrict__ M, const float* __restrict__ src,
    float* __restrict__ dst, float* __restrict__ dst2,
    const float* __restrict__ tyb, const float* __restrict__ tgb, float rbias,
    float* __restrict__ cw, const float* __restrict__ crd,
    float* s_v, float* sp, float* sout, float* s_c,
    float* hcorr, float* hpart, float* hself,
    float* hD1v, float* hZ1v, float* sG1v)
{
    const int tid = threadIdx.x;
    constexpr int ROWS = (MODE == 2) ? 16 : 32;
    constexpr int G = 256 / ROWS;
    constexpr int KTOT = (MODE == 3) ? 256 : 512;
    constexpr int KPG = KTOT / G;
    constexpr int LD = (MODE == 2) ? YY : HH;

    const int r = tid & (ROWS - 1);
    const int j = tid / ROWS;

    // ---- weight prefetch (issues before the polls; overlaps waiting) ----
    const float* col = M + (j * KPG) * LD + r;
    float wreg[KPG];
    #pragma unroll
    for (int k = 0; k < KPG; ++k) wreg[k] = col[k * LD];

    // ---- poll coefficients + fresh vector (self-announcing data) ----
    constexpr float P1 = (MODE == 0 || MODE == 1) ? 1.0f : 0.0f;
    cload_poll(crd, t, P1, lr, s_c);
    constexpr int NF = (MODE == 3) ? YY : HH;
    for (int i = tid; i < NF; i += 256) s_v[i] = pollf(src + i);
    __syncthreads();

    // ---- matvec: registers x LDS ----
    float a = 0.f;
    const float* vv = s_v + j * KPG;
    #pragma unroll
    for (int k = 0; k < KPG; ++k) a += wreg[k] * vv[k];
    const int lane = tid & 63, w = tid >> 6;
    float sres = 0.f;
    if constexpr (ROWS == 32) {
        a += __shfl_xor(a, 32);
        if (lane < 32) sp[w * 32 + lane] = a;
        __syncthreads();
        if (tid < 32) sres = sp[tid] + sp[32 + tid] + sp[64 + tid] + sp[96 + tid];
    } else {
        a += __shfl_xor(a, 16);
        a += __shfl_xor(a, 32);
        if (lane < 16) sp[w * 16 + lane] = a;
        __syncthreads();
        if (tid < 16) sres = sp[tid] + sp[16 + tid] + sp[32 + tid] + sp[48 + tid];
    }

    // ---- epilogue (LDS history only) ----
    if (tid < ROWS) {
        float corr = 0.f;
        for (int s = 0; s < t; ++s) corr += hcorr[s * ROWS + tid] * s_c[s];
        if constexpr (MODE == 5) {
            const float dz = (sres - corr) * ((hcorr[t * 32 + tid] > 0.f) ? 1.f : 0.f);
            axs(dst + t * HH + base + tid, dz);
            hD1v[t * 32 + tid] = dz;
            if (t + 1 < TT) {
                float cr = dz * sG1v[t * 16 + (t + 1)];
                for (int s = 0; s < t; ++s)
                    cr += hD1v[s * 32 + tid] * sG1v[s * 16 + (t + 1)];
                const float h1n = fmaxf(hZ1v[(t + 1) * 32 + tid] - lr * cr, 0.f);
                axs(dst2 + (t + 1) * HH + base + tid, h1n);
                hself[(t + 1) * 32 + tid] = h1n;
                sout[tid] = h1n;
            }
        } else {
            float v;
            if constexpr (MODE == 0)
                v = fmaxf(sres + rbias - corr, 0.f);
            else if constexpr (MODE == 1)
                v = fmaxf(sres + rbias - corr, 0.f) * tgb[t * HH + base + tid];
            else if constexpr (MODE == 2)
                v = (sres - corr - tyb[t * YY + base16 + tid]) * (2.0f / YY);
            else if constexpr (MODE == 3)
                v = (sres - corr) * tgb[t * HH + base + tid] *
                    ((hcorr[t * 32 + tid] > 0.f) ? 1.f : 0.f);
            else
                v = (sres - corr) * ((hcorr[t * 32 + tid] > 0.f) ? 1.f : 0.f);
            if constexpr (MODE == 2) axs(dst + t * YY + base16 + tid, v);
            else                     axs(dst + t * HH + base + tid, v);
            hself[t * ROWS + tid] = v;
            sout[tid] = v;
        }
    }
    __syncthreads();

    // ---- partials for next stage's coefficients (own region, write-once) ----
    const int tmax = (MODE == 5) ? ((t + 1 < TT) ? t : -1) : (t - 1);
    if constexpr (MODE == 2) partials16L(hpart, tmax, cw, blk, sout);
    else                     partials32L(hpart, tmax, cw, blk, sout);
    __syncthreads();   // LDS reuse safety for next stage
}

// ---------------------------------------------------------------------------
// Transpose W1..W4 (64x64 tiles), sentinel-prefill handoff buffers, inner_lr.
// grid: 192 blocks of 256
// ---------------------------------------------------------------------------
__global__ __launch_bounds__(256) void k_tr(
    const float* __restrict__ W1, const float* __restrict__ W2,
    const float* __restrict__ W3, const float* __restrict__ W4,
    float* __restrict__ WT1, float* __restrict__ WT2,
    float* __restrict__ WT3, float* __restrict__ WT4,
    const float* __restrict__ loglr, float* __restrict__ out,
    unsigned* __restrict__ hist0, unsigned* __restrict__ cpart0)
{
    const int tid = threadIdx.x;
    int bid = blockIdx.x;
    if (blockIdx.x == 0 && tid == 0) out[2048] = expf(loglr[0]);

    // Sentinel-prefill: histories (851968 words, contiguous) + cpart (393216).
    {
        const int gt = blockIdx.x * 256 + tid;       // 49152 threads
        for (long i = gt; i < 851968; i += 192 * 256) hist0[i] = SENTU;
        for (long i = gt; i < 393216; i += 192 * 256) cpart0[i] = SENTU;
    }

    const float* src; float* dst; int R, C;
    if (bid < 32)       { src = W1; dst = WT1; R = 512; C = 256; }
    else if (bid < 96)  { src = W2; dst = WT2; R = 512; C = 512; bid -= 32; }
    else if (bid < 160) { src = W3; dst = WT3; R = 512; C = 512; bid -= 96; }
    else                { src = W4; dst = WT4; R = 256; C = 512; bid -= 160; }
    const int tilesC = C >> 6;
    const int i0 = (bid / tilesC) * 64, j0 = (bid % tilesC) * 64;

    __shared__ float sm[64][65];
    #pragma unroll
    for (int rep = 0; rep < 16; ++rep) {
        const int flat = rep * 256 + tid;
        const int r = flat >> 6, c = flat & 63;
        sm[r][c] = src[(i0 + r) * C + j0 + c];
    }
    __syncthreads();
    #pragma unroll
    for (int rep = 0; rep < 16; ++rep) {
        const int flat = rep * 256 + tid;
        const int c = flat >> 6, r = flat & 63;
        dst[(j0 + c) * R + i0 + r] = sm[r][c];
    }
}

// ---------------------------------------------------------------------------
// Persistent inner loop, barrier-free (sentinel data-flow). 256 blocks of 256;
// 16 blocks/task, 32 rows/block. Every cross-block word is write-once.
// ---------------------------------------------------------------------------
__global__ __launch_bounds__(256, 1) void k_inner(
    const float* __restrict__ tx, const float* __restrict__ ty, const float* __restrict__ tg,
    const float* __restrict__ b1v, const float* __restrict__ b2v, const float* __restrict__ b3v,
    const float* __restrict__ W2, const float* __restrict__ W3, const float* __restrict__ W4,
    const float* __restrict__ WT1, const float* __restrict__ WT2, const float* __restrict__ WT3,
    const float* __restrict__ WT4, const float* __restrict__ loglr,
    float* __restrict__ H1, float* __restrict__ H2, float* __restrict__ HG,
    float* __restrict__ D1, float* __restrict__ D2, float* __restrict__ D3, float* __restrict__ D4,
    float* __restrict__ cpart)
{
    const int tid = threadIdx.x;
    const int lane = tid & 63, w = tid >> 6;
    const int g = blockIdx.x;
    const int b = g >> 4;
    const int blk = ((g & 7) << 1) | ((g >> 3) & 1);   // XCD-local weight rows
    const int base = blk * 32, base16 = blk * 16;
    const float lr = expf(loglr[0]);

    const float* txb = tx + b * (TT * XX);
    const float* tyb = ty + b * (TT * YY);
    const float* tgb = tg + b * (TT * HH);
    float* H1b = H1 + b * (TT * HH);
    float* H2b = H2 + b * (TT * HH);
    float* HGb = HG + b * (TT * HH);
    float* D1b = D1 + b * (TT * HH);
    float* D2b = D2 + b * (TT * HH);
    float* D3b = D3 + b * (TT * HH);
    float* D4b = D4 + b * (TT * YY);
    float* creg = cpart + (long)b * 96 * 256;   // per-task: 96 stage regions

    __shared__ float s_x[16 * 260];  // P0 only
    __shared__ float spz[2176];      // P0 only
    __shared__ __align__(16) float s_v[HH];
    __shared__ float sp[128];
    __shared__ float sout[32];
    __shared__ float s_c[16];
    // Block-private history (own 32/16-row slices), LDS-resident:
    __shared__ float hH1[TT * 32], hH2[TT * 32], hHG[TT * 32];
    __shared__ float hD1[TT * 32], hD2[TT * 32], hD3[TT * 32];
    __shared__ float hD4[TT * 16];
    __shared__ float hZ1[TT * 32];
    __shared__ float sG1[TT * 16];

    const float rb2 = (tid < 32) ? b2v[base + tid] : 0.f;
    const float rb3 = (tid < 32) ? b3v[base + tid] : 0.f;

    // ---------------- P0: Z1base (LDS), G1 (LDS, replicated), H1[0] ----------
    {
        const float4* src4 = (const float4*)txb;   // 1024 float4
        #pragma unroll
        for (int q = 0; q < 4; ++q) {
            const int idx = q * 256 + tid;
            const int tt = idx >> 6, k4 = idx & 63;
            *(float4*)&s_x[tt * 260 + k4 * 4] = src4[idx];
        }
    }
    __syncthreads();
    {
        const int r = tid & 31, j = tid >> 5;
        float acc[16];
        #pragma unroll
        for (int tt = 0; tt < 16; ++tt) acc[tt] = 0.f;
        const float* col = WT1 + (j * 32) * HH + base + r;
        #pragma unroll 4
        for (int kk = 0; kk < 32; ++kk) {
            const float wv = col[kk * HH];
            const int k = j * 32 + kk;
            #pragma unroll
            for (int tt = 0; tt < 16; ++tt) acc[tt] += wv * s_x[tt * 260 + k];
        }
        #pragma unroll
        for (int tt = 0; tt < 16; ++tt) {
            float a = acc[tt] + __shfl_xor(acc[tt], 32);
            if (lane < 32) spz[w * 544 + lane * 17 + tt] = a;
        }
        __syncthreads();
        const int rr = tid & 31, tp = tid >> 5;
        #pragma unroll
        for (int q = 0; q < 2; ++q) {
            const int tt = tp * 2 + q;
            const int row = base + rr;
            float v = spz[rr * 17 + tt] + spz[544 + rr * 17 + tt] +
                      spz[1088 + rr * 17 + tt] + spz[1632 + rr * 17 + tt];
            v += b1v[row];
            hZ1[tt * 32 + rr] = v;
            if (tt == 0) {
                const float h = fmaxf(v, 0.f);
                hH1[rr] = h;
                axs(&H1b[row], h);   // self-announces to F2@t=0 pollers
            }
        }
    }
    {   // Gram matrix, replicated per block
        const int ss = tid >> 4, uu = tid & 15;
        float a = 0.f;
        for (int k = 0; k < 256; ++k) a += s_x[ss * 260 + k] * s_x[uu * 260 + k];
        sG1[ss * 16 + uu] = a + 1.0f;
    }
    __syncthreads();

    // ---------------- Phase 1: 16 SGD steps x 6 stages, barrier-free --------
    int k = 0;
    #pragma unroll 1
    for (int t = 0; t < TT; ++t) {
        do_stage<0>(t, lr, base, base16, blk, WT2 + base, H1b + t * HH,
                    H2b, nullptr, tyb, tgb, rb2,
                    creg + (long)k * 256, creg + (long)(k ? k - 1 : 0) * 256,
                    s_v, sp, sout, s_c, hD2, hH2, hH2, hD1, hZ1, sG1);
        ++k;
        do_stage<1>(t, lr, base, base16, blk, WT3 + base, H2b + t * HH,
                    HGb, nullptr, tyb, tgb, rb3,
                    creg + (long)k * 256, creg + (long)(k - 1) * 256,
                    s_v, sp, sout, s_c, hD3, hHG, hHG, hD1, hZ1, sG1);
        ++k;
        do_stage<2>(t, lr, base, base16, blk, WT4 + base16, HGb + t * HH,
                    D4b, nullptr, tyb, tgb, 0.f,
                    creg + (long)k * 256, creg + (long)(k - 1) * 256,
                    s_v, sp, sout, s_c, hD4, hD4, hD4, hD1, hZ1, sG1);
        ++k;
        do_stage<3>(t, lr, base, base16, blk, W4 + base, D4b + t * YY,
                    D3b, nullptr, tyb, tgb, 0.f,
                    creg + (long)k * 256, creg + (long)(k - 1) * 256,
                    s_v, sp, sout, s_c, hHG, hD3, hD3, hD1, hZ1, sG1);
        ++k;
        do_stage<4>(t, lr, base, base16, blk, W3 + base, D3b + t * HH,
                    D2b, nullptr, tyb, tgb, 0.f,
                    creg + (long)k * 256, creg + (long)(k - 1) * 256,
                    s_v, sp, sout, s_c, hH2, hD2, hD2, hD1, hZ1, sG1);
        ++k;
        do_stage<5>(t, lr, base, base16, blk, W2 + base, D2b + t * HH,
                    D1b, H1b, tyb, tgb, 0.f,
                    creg + (long)k * 256, creg + (long)(k - 1) * 256,
                    s_v, sp, sout, s_c, hH1, hH1, hH1, hD1, hZ1, sG1);
        ++k;
    }
}

// ---------------------------------------------------------------------------
// Phase-2 fused layer — byte-identical to R11 (proven correct/deterministic).
// All k_inner-produced data read via agent atomic loads.
// ---------------------------------------------------------------------------
template <int K, int OUT, bool RELU, bool BIAS, bool PLUSONE>
__device__ __forceinline__ void p2_layer(
    const float* __restrict__ WT,      // [K][OUT]
    const float* __restrict__ bias,    // [OUT] or null
    const float* __restrict__ Dj,      // [16][OUT]  (k_inner output)
    const float* __restrict__ Asrc,    // [16][K]    (k_inner output / input)
    float lr, float* sact, float* sactN, float* sWA)
{
    constexpr int KE = (K + 16 + 63) & ~63;   // 320 / 576
    constexpr int KPG = KE / 16;              // 20 / 36 (multiple of 4)
    constexpr int SAP = K + 4;                // sA pitch (bank spread)
    const int tid = threadIdx.x;

    // ---- stage A rows into LDS (coherent 64-bit atomic loads) ----
    float* sA = sWA;   // [16][SAP]
    {
        constexpr int KH = K / 2;
        for (int i = tid; i < 16 * KH; i += 512) {
            const int s = i / KH, c = i - s * KH;
            *(u64*)(sA + s * SAP + c * 2) =
                ald8((const u64*)(Asrc + (long)s * K) + c);
        }
    }
    __syncthreads();

    // ---- ip[s][l] -> sact[l][K+s] = -lr*(A_s . act_l + plus1) ----
    {
        const int s = tid >> 5, lq = tid & 31;
        const int l = lq >> 2, q = lq & 3;
        const float4* av = (const float4*)(sA + s * SAP + q * (K / 4));
        const float4* xv = (const float4*)(sact + l * PW + q * (K / 4));
        float a = 0.f;
        for (int k = 0; k < K / 16; ++k) {
            const float4 u = av[k], x = xv[k];
            a += u.x * x.x + u.y * x.y + u.z * x.z + u.w * x.w;
        }
        a += __shfl_xor(a, 1);
        a += __shfl_xor(a, 2);
        if (q == 0) sact[l * PW + K + s] = -lr * (a + (PLUSONE ? 1.f : 0.f));
    }
    __syncthreads();

    // ---- GEMM ----
    float* sP = sWA;   // [16][64][9] partials (sA dead after ip step)
    const int r = tid & 31, j = tid >> 5;    // j in 0..15
    const float* xb = sact + j * KPG;
    for (int nc = 0; nc < OUT / 64; ++nc) {
        const int n0 = nc * 64 + r;
        float a0[8], a1[8];
        #pragma unroll
        for (int l = 0; l < 8; ++l) { a0[l] = 0.f; a1[l] = 0.f; }
        if ((j + 1) * KPG <= K) {
            const float* c0 = WT + (long)(j * KPG) * OUT + n0;
            #pragma unroll 4
            for (int kk = 0; kk < KPG; kk += 4) {
                float w00, w01, w02, w03, w10, w11, w12, w13;
                w00 = c0[(long)(kk + 0) * OUT]; w10 = c0[(long)(kk + 0) * OUT + 32];
                w01 = c0[(long)(kk + 1) * OUT]; w11 = c0[(long)(kk + 1) * OUT + 32];
                w02 = c0[(long)(kk + 2) * OUT]; w12 = c0[(long)(kk + 2) * OUT + 32];
                w03 = c0[(long)(kk + 3) * OUT]; w13 = c0[(long)(kk + 3) * OUT + 32];
                #pragma unroll
                for (int l = 0; l < 8; ++l) {
                    const float4 x = *(const float4*)&xb[l * PW + kk];
                    a0[l] += w00 * x.x; a0[l] += w01 * x.y;
                    a0[l] += w02 * x.z; a0[l] += w03 * x.w;
                    a1[l] += w10 * x.x; a1[l] += w11 * x.y;
                    a1[l] += w12 * x.z; a1[l] += w13 * x.w;
                }
            }
        } else {
            #pragma unroll 4
            for (int kk = 0; kk < KPG; kk += 4) {
                float w0q[4], w1q[4];
                #pragma unroll
                for (int q = 0; q < 4; ++q) {
                    const int k = j * KPG + kk + q;
                    w0q[q] = (k < K) ? WT[(long)k * OUT + n0]
                           : (k < K + 16) ? ald(&Dj[(k - K) * OUT + n0]) : 0.f;
                    w1q[q] = (k < K) ? WT[(long)k * OUT + n0 + 32]
                           : (k < K + 16) ? ald(&Dj[(k - K) * OUT + n0 + 32]) : 0.f;
                }
                #pragma unroll
                for (int l = 0; l < 8; ++l) {
                    const float4 x = *(const float4*)&xb[l * PW + kk];
                    a0[l] += w0q[0] * x.x; a0[l] += w0q[1] * x.y;
                    a0[l] += w0q[2] * x.z; a0[l] += w0q[3] * x.w;
                    a1[l] += w1q[0] * x.x; a1[l] += w1q[1] * x.y;
                    a1[l] += w1q[2] * x.z; a1[l] += w1q[3] * x.w;
                }
            }
        }
        __syncthreads();   // sP region free (vs sA / previous reduce reads)
        #pragma unroll
        for (int l = 0; l < 8; ++l) {
            sP[(j * 64 + r) * 9 + l]      = a0[l];
            sP[(j * 64 + 32 + r) * 9 + l] = a1[l];
        }
        __syncthreads();
        {   // 16-way reduce: exactly one output per thread (64 n x 8 l = 512)
            const int nn = tid >> 3, ll = tid & 7;
            float v = 0.f;
            #pragma unroll
            for (int q = 0; q < 16; ++q) v += sP[(q * 64 + nn) * 9 + ll];
            const int n = nc * 64 + nn;
            if (BIAS) v += bias[n];
            if (RELU) v = fmaxf(v, 0.f);
            sactN[ll * PW + n] = v;
        }
    }
    __syncthreads();
    // zero-pad cols [OUT+16, PW) of the output for the next consumer
    constexpr int ZC = PW - (OUT + 16);
    for (int f = tid; f < 8 * ZC; f += 512) {
        const int l = f / ZC, c = f - l * ZC;
        sactN[l * PW + OUT + 16 + c] = 0.f;
    }
    __syncthreads();
}

// ---------------------------------------------------------------------------
// Phase-2: test forward + loss, fully block-local. grid 256 blocks of 512.
// ---------------------------------------------------------------------------
__global__ __launch_bounds__(512, 1) void k_p2(
    const float* __restrict__ tx, const float* __restrict__ tex,
    const float* __restrict__ tey, const float* __restrict__ teg,
    const float* __restrict__ b1v, const float* __restrict__ b2v,
    const float* __restrict__ b3v,
    const float* __restrict__ WT1, const float* __restrict__ WT2,
    const float* __restrict__ WT3, const float* __restrict__ WT4,
    const float* __restrict__ H1, const float* __restrict__ H2,
    const float* __restrict__ HG,
    const float* __restrict__ D1, const float* __restrict__ D2,
    const float* __restrict__ D3, const float* __restrict__ D4,
    const float* __restrict__ loglr, float* __restrict__ outp)
{
    const int tid = threadIdx.x;
    const int b = blockIdx.x >> 4;
    const int l0 = (blockIdx.x & 15) * 8;
    const float lr = expf(loglr[0]);

    __shared__ __align__(16) float pool[18624];   // ~74.5 KB
    float* a0  = pool;            // act buffers [8][PW]
    float* a1  = pool + 4704;     // 8*588
    float* sWA = pool + 9408;     // scratch: sA [16][K+4] / sP [16][64][9]

    const float* txb = tx + b * (TT * XX);
    const float* H1b = H1 + b * (TT * HH);
    const float* H2b = H2 + b * (TT * HH);
    const float* HGb = HG + b * (TT * HH);
    const float* D1b = D1 + b * (TT * HH);
    const float* D2b = D2 + b * (TT * HH);
    const float* D3b = D3 + b * (TT * HH);
    const float* D4b = D4 + b * (TT * YY);

    // stage tex rows (zero-padded to PW)
    for (int f = tid; f < 8 * PW; f += 512) {
        const int l = f / PW, c = f - l * PW;
        a0[f] = (c < XX) ? tex[((long)b * LL + l0 + l) * XX + c] : 0.f;
    }
    __syncthreads();

    p2_layer<XX, HH, true, true, true>(WT1, b1v, D1b, txb, lr, a0, a1, sWA);
    p2_layer<HH, HH, true, true, true>(WT2, b2v, D2b, H1b, lr, a1, a0, sWA);
    p2_layer<HH, HH, true, true, true>(WT3, b3v, D3b, H2b, lr, a0, a1, sWA);

    // gate act3 with test_gate
    for (int f = tid; f < 8 * HH; f += 512) {
        const int l = f >> 9, k = f & 511;
        a1[l * PW + k] *= teg[((long)b * LL + l0 + l) * HH + k];
    }
    __syncthreads();

    p2_layer<HH, YY, false, false, false>(WT4, nullptr, D4b, HGb, lr, a1, a0, sWA);

    // logits out
    for (int f = tid; f < 8 * YY; f += 512) {
        const int l = f >> 8, y = f & 255;
        outp[4097 + ((long)(b * LL + l0 + l)) * YY + y] = a0[l * PW + y];
    }
    // loss + evaluation (first 256 threads: 8 l x 32 lanes)
    if (tid < 256) {
        const int l = tid >> 5, kk = tid & 31;
        float a = 0.f;
        #pragma unroll
        for (int jj = 0; jj < 8; ++jj) {
            const int y = kk * 8 + jj;
            const float d = a0[l * PW + y] -
                            tey[((long)b * LL + l0 + l) * YY + y];
            a += d * d;
        }
        a += __shfl_xor(a, 1);
        a += __shfl_xor(a, 2);
        a += __shfl_xor(a, 4);
        a += __shfl_xor(a, 8);
        a += __shfl_xor(a, 16);
        if (kk == 0) {
            const float v = a * (1.0f / YY);
            const int idx = b * LL + l0 + l;
            outp[idx] = v;
            outp[2049 + idx] = v;
        }
    }
}

// ---------------------------------------------------------------------------
extern "C" void kernel_launch(void* const* d_in, const int* in_sizes, int n_in,
                              void* d_out, int out_size, void* d_ws, size_t ws_size,
                              hipStream_t stream)
{
    const float* tx    = (const float*)d_in[0];   // train_x  [B][T][X]
    const float* ty    = (const float*)d_in[1];   // train_y  [B][T][Y]
    const float* tex   = (const float*)d_in[2];   // test_x   [B][L][X]
    const float* tey   = (const float*)d_in[3];   // test_y   [B][L][Y]
    const float* tg    = (const float*)d_in[4];   // train_gate [B][T][H]
    const float* teg   = (const float*)d_in[5];   // test_gate  [B][L][H]
    const float* W1    = (const float*)d_in[6];
    const float* b1    = (const float*)d_in[7];
    const float* W2    = (const float*)d_in[8];
    const float* b2    = (const float*)d_in[9];
    const float* W3    = (const float*)d_in[10];
    const float* b3    = (const float*)d_in[11];
    const float* W4    = (const float*)d_in[12];
    const float* loglr = (const float*)d_in[13];

    float* out = (float*)d_out;
    float* ws  = (float*)d_ws;

    // workspace layout (floats). H1..D4 are contiguous (851968 words) and
    // sentinel-prefilled by k_tr. cpart lives in the unused ActB region.
    float* H1     = ws + 135168;        // 131072
    float* H2     = ws + 266240;        // 131072
    float* HG     = ws + 397312;        // 131072
    float* D1     = ws + 528384;        // 131072
    float* D2     = ws + 659456;        // 131072
    float* D3     = ws + 790528;        // 131072
    float* D4     = ws + 921600;        // 65536
    float* ActA   = ws + 1024000;       // holds WT1..WT4
    float* WT1    = ActA;               // [256][512] = 131072
    float* WT2    = ActA + 131072;      // [512][512] = 262144
    float* WT3    = ActA + 393216;      // [512][512] = 262144
    float* WT4    = ActA + 655360;      // [512][256] = 131072
    float* cpart  = ws + 2072576;       // 16 tasks x 96 stages x 256 = 393216

    // Transpose weights + sentinel-prefill handoff buffers + inner_lr.
    k_tr<<<192, 256, 0, stream>>>(W1, W2, W3, W4, WT1, WT2, WT3, WT4, loglr,
                                  out, (unsigned*)H1, (unsigned*)cpart);

    // 16-step MAML inner loop (persistent, barrier-free sentinel data-flow).
    k_inner<<<TB * 16, 256, 0, stream>>>(tx, ty, tg, b1, b2, b3, W2, W3, W4,
                                         WT1, WT2, WT3, WT4, loglr,
                                         H1, H2, HG, D1, D2, D3, D4, cpart);

    // Phase 2: test-set forward + loss, one block-local dispatch (512 thr).
    k_p2<<<TB * 16, 512, 0, stream>>>(tx, tex, tey, teg, b1, b2, b3,
                                      WT1, WT2, WT3, WT4,
                                      H1, H2, HG, D1, D2, D3, D4,
                                      loglr, out);
}

// Round 14
// 495.946 us; speedup vs baseline: 2.3880x; 1.1327x over previous
//
#include <hip/hip_runtime.h>
#include <math.h>

// Problem dims
#define TB 16   // batch (tasks)
#define TT 16   // train steps
#define LL 128  // test length
#define XX 256  // x dim
#define HH 512  // hidden
#define YY 256  // y dim

#define PW 588  // phase-2 act row pitch
#define SENTU 0xFFC0DEADu   // sentinel: NaN payload, never produced by finite math

typedef unsigned long long u64;

// ---------------------------------------------------------------------------
// Cross-block primitives (all agent-scope, coherent-point).
// WRITE: no-return atomic exchange — executes at the coherent point, no
//   response wait. Safe because readers poll the DATA ITSELF (sentinel
//   protocol) — no separate flag whose ordering could race (the R8-R10 bug).
// READ: atomic loads (bypass L1/L2).
// ---------------------------------------------------------------------------
__device__ __forceinline__ void axs(float* p, float v) {
    (void)__hip_atomic_exchange(p, v, __ATOMIC_RELAXED, __HIP_MEMORY_SCOPE_AGENT);
}
__device__ __forceinline__ float ald(const float* p) {
    return __hip_atomic_load(p, __ATOMIC_RELAXED, __HIP_MEMORY_SCOPE_AGENT);
}
__device__ __forceinline__ unsigned aldu(const unsigned* p) {
    return __hip_atomic_load(p, __ATOMIC_RELAXED, __HIP_MEMORY_SCOPE_AGENT);
}
__device__ __forceinline__ u64 ald8(const u64* p) {
    return __hip_atomic_load(p, __ATOMIC_RELAXED, __HIP_MEMORY_SCOPE_AGENT);
}

// Partial dots of fresh slice (sout) against own LDS history rows s <= tmax.
__device__ __forceinline__ void partials32L(const float* hist, int tmax,
                                            float* cpw, int blk, const float* sout) {
    const int tid = threadIdx.x;
    const int s2 = tid >> 4, i = tid & 15;
    float pp = 0.f;
    const bool act = (s2 <= tmax);
    if (act) {
        pp = hist[s2 * 32 + 2 * i] * sout[2 * i] +
             hist[s2 * 32 + 2 * i + 1] * sout[2 * i + 1];
    }
    pp += __shfl_xor(pp, 1);
    pp += __shfl_xor(pp, 2);
    pp += __shfl_xor(pp, 4);
    pp += __shfl_xor(pp, 8);
    if (act && i == 0) axs(&cpw[s2 * 16 + blk], pp);
}

__device__ __forceinline__ void partials16L(const float* hist, int tmax,
                                            float* cpw, int blk, const float* sout) {
    const int tid = threadIdx.x;
    const int s2 = tid >> 4, i = tid & 15;
    float pp = 0.f;
    const bool act = (s2 <= tmax);
    if (act) pp = hist[s2 * 16 + i] * sout[i];
    pp += __shfl_xor(pp, 1);
    pp += __shfl_xor(pp, 2);
    pp += __shfl_xor(pp, 4);
    pp += __shfl_xor(pp, 8);
    if (act && i == 0) axs(&cpw[s2 * 16 + blk], pp);
}

// ---------------------------------------------------------------------------
// One phase-1 stage. MODE: 0=F2 1=F3 2=F4 3=B4 4=B3 5=B2(+h1_{t+1}).
// Barrier-free; BATCHED polling: every thread issues ALL its loads (2 coeff
// words for tid<128, 1-2 fresh-vector words) back-to-back, then re-loads only
// still-sentinel words — 1 coherent-point RT instead of R13's 2-4 serial RTs.
// FP summation order identical to R13.
// ---------------------------------------------------------------------------
template <int MODE>
__device__ __forceinline__ void do_stage(
    int t, float lr, int base, int base16, int blk,
    const float* __restrict__ M, const float* __restrict__ src,
    float* __restrict__ dst, float* __restrict__ dst2,
    const float* __restrict__ tyb, const float* __restrict__ tgb, float rbias,
    float* __restrict__ cw, const float* __restrict__ crd,
    float* s_v, float* sp, float* sout, float* s_c,
    float* hcorr, float* hpart, float* hself,
    float* hD1v, float* hZ1v, float* sG1v)
{
    const int tid = threadIdx.x;
    constexpr int ROWS = (MODE == 2) ? 16 : 32;
    constexpr int G = 256 / ROWS;
    constexpr int KTOT = (MODE == 3) ? 256 : 512;
    constexpr int KPG = KTOT / G;
    constexpr int LD = (MODE == 2) ? YY : HH;

    const int r = tid & (ROWS - 1);
    const int j = tid / ROWS;

    // ---- weight prefetch (issues before the polls; overlaps waiting) ----
    const float* col = M + (j * KPG) * LD + r;
    float wreg[KPG];
    #pragma unroll
    for (int k = 0; k < KPG; ++k) wreg[k] = col[k * LD];

    // ---- combined batched poll: coefficients + fresh vector ----
    constexpr float P1 = (MODE == 0 || MODE == 1) ? 1.0f : 0.0f;
    constexpr int NF = (MODE == 3) ? YY : HH;
    {
        const int cs = tid >> 3, cj = tid & 7;
        const bool haveC = (tid < 128) && (cs < t);
        const unsigned* cp = (const unsigned*)(crd + cs * 16 + 2 * cj);
        const unsigned* vp = (const unsigned*)src;
        unsigned c0 = 0u, c1 = 0u, v1 = 0u;
        // issue all loads back-to-back (independent -> 1 RT)
        unsigned v0 = aldu(vp + tid);
        if (NF == 512) v1 = aldu(vp + tid + 256);
        if (haveC) { c0 = aldu(cp); c1 = aldu(cp + 1); }
        while ((v0 == SENTU) | ((NF == 512) & (v1 == SENTU)) |
               (haveC & ((c0 == SENTU) | (c1 == SENTU)))) {
            __builtin_amdgcn_s_sleep(1);
            if (v0 == SENTU) v0 = aldu(vp + tid);
            if (NF == 512 && v1 == SENTU) v1 = aldu(vp + tid + 256);
            if (haveC && c0 == SENTU) c0 = aldu(cp);
            if (haveC && c1 == SENTU) c1 = aldu(cp + 1);
        }
        s_v[tid] = __uint_as_float(v0);
        if (NF == 512) s_v[tid + 256] = __uint_as_float(v1);
        if (tid < 128) {
            float v = haveC ? (__uint_as_float(c0) + __uint_as_float(c1)) : 0.f;
            v += __shfl_xor(v, 1);
            v += __shfl_xor(v, 2);
            v += __shfl_xor(v, 4);
            if (cj == 0) s_c[cs] = lr * (v + P1);
        }
    }
    __syncthreads();

    // ---- matvec: registers x LDS ----
    float a = 0.f;
    const float* vv = s_v + j * KPG;
    #pragma unroll
    for (int k = 0; k < KPG; ++k) a += wreg[k] * vv[k];
    const int lane = tid & 63, w = tid >> 6;
    float sres = 0.f;
    if constexpr (ROWS == 32) {
        a += __shfl_xor(a, 32);
        if (lane < 32) sp[w * 32 + lane] = a;
        __syncthreads();
        if (tid < 32) sres = sp[tid] + sp[32 + tid] + sp[64 + tid] + sp[96 + tid];
    } else {
        a += __shfl_xor(a, 16);
        a += __shfl_xor(a, 32);
        if (lane < 16) sp[w * 16 + lane] = a;
        __syncthreads();
        if (tid < 16) sres = sp[tid] + sp[16 + tid] + sp[32 + tid] + sp[48 + tid];
    }

    // ---- epilogue (LDS history only) ----
    if (tid < ROWS) {
        float corr = 0.f;
        for (int s = 0; s < t; ++s) corr += hcorr[s * ROWS + tid] * s_c[s];
        if constexpr (MODE == 5) {
            const float dz = (sres - corr) * ((hcorr[t * 32 + tid] > 0.f) ? 1.f : 0.f);
            axs(dst + t * HH + base + tid, dz);
            hD1v[t * 32 + tid] = dz;
            if (t + 1 < TT) {
                float cr = dz * sG1v[t * 16 + (t + 1)];
                for (int s = 0; s < t; ++s)
                    cr += hD1v[s * 32 + tid] * sG1v[s * 16 + (t + 1)];
                const float h1n = fmaxf(hZ1v[(t + 1) * 32 + tid] - lr * cr, 0.f);
                axs(dst2 + (t + 1) * HH + base + tid, h1n);
                hself[(t + 1) * 32 + tid] = h1n;
                sout[tid] = h1n;
            }
        } else {
            float v;
            if constexpr (MODE == 0)
                v = fmaxf(sres + rbias - corr, 0.f);
            else if constexpr (MODE == 1)
                v = fmaxf(sres + rbias - corr, 0.f) * tgb[t * HH + base + tid];
            else if constexpr (MODE == 2)
                v = (sres - corr - tyb[t * YY + base16 + tid]) * (2.0f / YY);
            else if constexpr (MODE == 3)
                v = (sres - corr) * tgb[t * HH + base + tid] *
                    ((hcorr[t * 32 + tid] > 0.f) ? 1.f : 0.f);
            else
                v = (sres - corr) * ((hcorr[t * 32 + tid] > 0.f) ? 1.f : 0.f);
            if constexpr (MODE == 2) axs(dst + t * YY + base16 + tid, v);
            else                     axs(dst + t * HH + base + tid, v);
            hself[t * ROWS + tid] = v;
            sout[tid] = v;
        }
    }
    __syncthreads();

    // ---- partials for next stage's coefficients (own region, write-once) ----
    const int tmax = (MODE == 5) ? ((t + 1 < TT) ? t : -1) : (t - 1);
    if constexpr (MODE == 2) partials16L(hpart, tmax, cw, blk, sout);
    else                     partials32L(hpart, tmax, cw, blk, sout);
    __syncthreads();   // LDS reuse safety for next stage
}

// ---------------------------------------------------------------------------
// Transpose W1..W4 (64x64 tiles), sentinel-prefill handoff buffers, inner_lr.
// grid: 192 blocks of 256
// ---------------------------------------------------------------------------
__global__ __launch_bounds__(256) void k_tr(
    const float* __restrict__ W1, const float* __restrict__ W2,
    const float* __restrict__ W3, const float* __restrict__ W4,
    float* __restrict__ WT1, float* __restrict__ WT2,
    float* __restrict__ WT3, float* __restrict__ WT4,
    const float* __restrict__ loglr, float* __restrict__ out,
    unsigned* __restrict__ hist0, unsigned* __restrict__ cpart0)
{
    const int tid = threadIdx.x;
    int bid = blockIdx.x;
    if (blockIdx.x == 0 && tid == 0) out[2048] = expf(loglr[0]);

    // Sentinel-prefill: histories (851968 words, contiguous) + cpart (393216).
    {
        const int gt = blockIdx.x * 256 + tid;       // 49152 threads
        for (long i = gt; i < 851968; i += 192 * 256) hist0[i] = SENTU;
        for (long i = gt; i < 393216; i += 192 * 256) cpart0[i] = SENTU;
    }

    const float* src; float* dst; int R, C;
    if (bid < 32)       { src = W1; dst = WT1; R = 512; C = 256; }
    else if (bid < 96)  { src = W2; dst = WT2; R = 512; C = 512; bid -= 32; }
    else if (bid < 160) { src = W3; dst = WT3; R = 512; C = 512; bid -= 96; }
    else                { src = W4; dst = WT4; R = 256; C = 512; bid -= 160; }
    const int tilesC = C >> 6;
    const int i0 = (bid / tilesC) * 64, j0 = (bid % tilesC) * 64;

    __shared__ float sm[64][65];
    #pragma unroll
    for (int rep = 0; rep < 16; ++rep) {
        const int flat = rep * 256 + tid;
        const int r = flat >> 6, c = flat & 63;
        sm[r][c] = src[(i0 + r) * C + j0 + c];
    }
    __syncthreads();
    #pragma unroll
    for (int rep = 0; rep < 16; ++rep) {
        const int flat = rep * 256 + tid;
        const int c = flat >> 6, r = flat & 63;
        dst[(j0 + c) * R + i0 + r] = sm[r][c];
    }
}

// ---------------------------------------------------------------------------
// Persistent inner loop, barrier-free (sentinel data-flow). 256 blocks of 256;
// 16 blocks/task, 32 rows/block. Every cross-block word is write-once.
// ---------------------------------------------------------------------------
__global__ __launch_bounds__(256, 1) void k_inner(
    const float* __restrict__ tx, const float* __restrict__ ty, const float* __restrict__ tg,
    const float* __restrict__ b1v, const float* __restrict__ b2v, const float* __restrict__ b3v,
    const float* __restrict__ W2, const float* __restrict__ W3, const float* __restrict__ W4,
    const float* __restrict__ WT1, const float* __restrict__ WT2, const float* __restrict__ WT3,
    const float* __restrict__ WT4, const float* __restrict__ loglr,
    float* __restrict__ H1, float* __restrict__ H2, float* __restrict__ HG,
    float* __restrict__ D1, float* __restrict__ D2, float* __restrict__ D3, float* __restrict__ D4,
    float* __restrict__ cpart)
{
    const int tid = threadIdx.x;
    const int lane = tid & 63, w = tid >> 6;
    const int g = blockIdx.x;
    const int b = g >> 4;
    const int blk = ((g & 7) << 1) | ((g >> 3) & 1);   // XCD-local weight rows
    const int base = blk * 32, base16 = blk * 16;
    const float lr = expf(loglr[0]);

    const float* txb = tx + b * (TT * XX);
    const float* tyb = ty + b * (TT * YY);
    const float* tgb = tg + b * (TT * HH);
    float* H1b = H1 + b * (TT * HH);
    float* H2b = H2 + b * (TT * HH);
    float* HGb = HG + b * (TT * HH);
    float* D1b = D1 + b * (TT * HH);
    float* D2b = D2 + b * (TT * HH);
    float* D3b = D3 + b * (TT * HH);
    float* D4b = D4 + b * (TT * YY);
    float* creg = cpart + (long)b * 96 * 256;   // per-task: 96 stage regions

    __shared__ float s_x[16 * 260];  // P0 only
    __shared__ float spz[2176];      // P0 only
    __shared__ __align__(16) float s_v[HH];
    __shared__ float sp[128];
    __shared__ float sout[32];
    __shared__ float s_c[16];
    // Block-private history (own 32/16-row slices), LDS-resident:
    __shared__ float hH1[TT * 32], hH2[TT * 32], hHG[TT * 32];
    __shared__ float hD1[TT * 32], hD2[TT * 32], hD3[TT * 32];
    __shared__ float hD4[TT * 16];
    __shared__ float hZ1[TT * 32];
    __shared__ float sG1[TT * 16];

    const float rb2 = (tid < 32) ? b2v[base + tid] : 0.f;
    const float rb3 = (tid < 32) ? b3v[base + tid] : 0.f;

    // ---------------- P0: Z1base (LDS), G1 (LDS, replicated), H1[0] ----------
    {
        const float4* src4 = (const float4*)txb;   // 1024 float4
        #pragma unroll
        for (int q = 0; q < 4; ++q) {
            const int idx = q * 256 + tid;
            const int tt = idx >> 6, k4 = idx & 63;
            *(float4*)&s_x[tt * 260 + k4 * 4] = src4[idx];
        }
    }
    __syncthreads();
    {
        const int r = tid & 31, j = tid >> 5;
        float acc[16];
        #pragma unroll
        for (int tt = 0; tt < 16; ++tt) acc[tt] = 0.f;
        const float* col = WT1 + (j * 32) * HH + base + r;
        #pragma unroll 4
        for (int kk = 0; kk < 32; ++kk) {
            const float wv = col[kk * HH];
            const int k = j * 32 + kk;
            #pragma unroll
            for (int tt = 0; tt < 16; ++tt) acc[tt] += wv * s_x[tt * 260 + k];
        }
        #pragma unroll
        for (int tt = 0; tt < 16; ++tt) {
            float a = acc[tt] + __shfl_xor(acc[tt], 32);
            if (lane < 32) spz[w * 544 + lane * 17 + tt] = a;
        }
        __syncthreads();
        const int rr = tid & 31, tp = tid >> 5;
        #pragma unroll
        for (int q = 0; q < 2; ++q) {
            const int tt = tp * 2 + q;
            const int row = base + rr;
            float v = spz[rr * 17 + tt] + spz[544 + rr * 17 + tt] +
                      spz[1088 + rr * 17 + tt] + spz[1632 + rr * 17 + tt];
            v += b1v[row];
            hZ1[tt * 32 + rr] = v;
            if (tt == 0) {
                const float h = fmaxf(v, 0.f);
                hH1[rr] = h;
                axs(&H1b[row], h);   // self-announces to F2@t=0 pollers
            }
        }
    }
    {   // Gram matrix, replicated per block
        const int ss = tid >> 4, uu = tid & 15;
        float a = 0.f;
        for (int k = 0; k < 256; ++k) a += s_x[ss * 260 + k] * s_x[uu * 260 + k];
        sG1[ss * 16 + uu] = a + 1.0f;
    }
    __syncthreads();

    // ---------------- Phase 1: 16 SGD steps x 6 stages, barrier-free --------
    int k = 0;
    #pragma unroll 1
    for (int t = 0; t < TT; ++t) {
        do_stage<0>(t, lr, base, base16, blk, WT2 + base, H1b + t * HH,
                    H2b, nullptr, tyb, tgb, rb2,
                    creg + (long)k * 256, creg + (long)(k ? k - 1 : 0) * 256,
                    s_v, sp, sout, s_c, hD2, hH2, hH2, hD1, hZ1, sG1);
        ++k;
        do_stage<1>(t, lr, base, base16, blk, WT3 + base, H2b + t * HH,
                    HGb, nullptr, tyb, tgb, rb3,
                    creg + (long)k * 256, creg + (long)(k - 1) * 256,
                    s_v, sp, sout, s_c, hD3, hHG, hHG, hD1, hZ1, sG1);
        ++k;
        do_stage<2>(t, lr, base, base16, blk, WT4 + base16, HGb + t * HH,
                    D4b, nullptr, tyb, tgb, 0.f,
                    creg + (long)k * 256, creg + (long)(k - 1) * 256,
                    s_v, sp, sout, s_c, hD4, hD4, hD4, hD1, hZ1, sG1);
        ++k;
        do_stage<3>(t, lr, base, base16, blk, W4 + base, D4b + t * YY,
                    D3b, nullptr, tyb, tgb, 0.f,
                    creg + (long)k * 256, creg + (long)(k - 1) * 256,
                    s_v, sp, sout, s_c, hHG, hD3, hD3, hD1, hZ1, sG1);
        ++k;
        do_stage<4>(t, lr, base, base16, blk, W3 + base, D3b + t * HH,
                    D2b, nullptr, tyb, tgb, 0.f,
                    creg + (long)k * 256, creg + (long)(k - 1) * 256,
                    s_v, sp, sout, s_c, hH2, hD2, hD2, hD1, hZ1, sG1);
        ++k;
        do_stage<5>(t, lr, base, base16, blk, W2 + base, D2b + t * HH,
                    D1b, H1b, tyb, tgb, 0.f,
                    creg + (long)k * 256, creg + (long)(k - 1) * 256,
                    s_v, sp, sout, s_c, hH1, hH1, hH1, hD1, hZ1, sG1);
        ++k;
    }
}

// ---------------------------------------------------------------------------
// Phase-2 fused layer — logic identical to R13 (proven correct); Asrc staging
// now issues all per-thread atomic loads into statically-indexed registers
// before any use (ILP: 4-8 loads in flight instead of one-at-a-time).
// ---------------------------------------------------------------------------
template <int K, int OUT, bool RELU, bool BIAS, bool PLUSONE>
__device__ __forceinline__ void p2_layer(
    const float* __restrict__ WT,      // [K][OUT]
    const float* __restrict__ bias,    // [OUT] or null
    const float* __restrict__ Dj,      // [16][OUT]  (k_inner output)
    const float* __restrict__ Asrc,    // [16][K]    (k_inner output / input)
    float lr, float* sact, float* sactN, float* sWA)
{
    constexpr int KE = (K + 16 + 63) & ~63;   // 320 / 576
    constexpr int KPG = KE / 16;              // 20 / 36 (multiple of 4)
    constexpr int SAP = K + 4;                // sA pitch (bank spread)
    const int tid = threadIdx.x;

    // ---- stage A rows into LDS (batched coherent 64-bit atomic loads) ----
    float* sA = sWA;   // [16][SAP]
    {
        constexpr int TOT = 16 * (K / 2);     // u64 count: 4096 / 2048
        constexpr int PER = TOT / 512;        // 8 / 4
        u64 tmp[PER];
        #pragma unroll
        for (int q = 0; q < PER; ++q)
            tmp[q] = ald8((const u64*)Asrc + tid + q * 512);
        #pragma unroll
        for (int q = 0; q < PER; ++q) {
            const int idx = tid + q * 512;
            const int s = idx / (K / 2), c = idx - s * (K / 2);
            *(u64*)(sA + s * SAP + c * 2) = tmp[q];
        }
    }
    __syncthreads();

    // ---- ip[s][l] -> sact[l][K+s] = -lr*(A_s . act_l + plus1) ----
    {
        const int s = tid >> 5, lq = tid & 31;
        const int l = lq >> 2, q = lq & 3;
        const float4* av = (const float4*)(sA + s * SAP + q * (K / 4));
        const float4* xv = (const float4*)(sact + l * PW + q * (K / 4));
        float a = 0.f;
        for (int k = 0; k < K / 16; ++k) {
            const float4 u = av[k], x = xv[k];
            a += u.x * x.x + u.y * x.y + u.z * x.z + u.w * x.w;
        }
        a += __shfl_xor(a, 1);
        a += __shfl_xor(a, 2);
        if (q == 0) sact[l * PW + K + s] = -lr * (a + (PLUSONE ? 1.f : 0.f));
    }
    __syncthreads();

    // ---- GEMM ----
    float* sP = sWA;   // [16][64][9] partials (sA dead after ip step)
    const int r = tid & 31, j = tid >> 5;    // j in 0..15
    const float* xb = sact + j * KPG;
    for (int nc = 0; nc < OUT / 64; ++nc) {
        const int n0 = nc * 64 + r;
        float a0[8], a1[8];
        #pragma unroll
        for (int l = 0; l < 8; ++l) { a0[l] = 0.f; a1[l] = 0.f; }
        if ((j + 1) * KPG <= K) {
            const float* c0 = WT + (long)(j * KPG) * OUT + n0;
            #pragma unroll 4
            for (int kk = 0; kk < KPG; kk += 4) {
                float w00, w01, w02, w03, w10, w11, w12, w13;
                w00 = c0[(long)(kk + 0) * OUT]; w10 = c0[(long)(kk + 0) * OUT + 32];
                w01 = c0[(long)(kk + 1) * OUT]; w11 = c0[(long)(kk + 1) * OUT + 32];
                w02 = c0[(long)(kk + 2) * OUT]; w12 = c0[(long)(kk + 2) * OUT + 32];
                w03 = c0[(long)(kk + 3) * OUT]; w13 = c0[(long)(kk + 3) * OUT + 32];
                #pragma unroll
                for (int l = 0; l < 8; ++l) {
                    const float4 x = *(const float4*)&xb[l * PW + kk];
                    a0[l] += w00 * x.x; a0[l] += w01 * x.y;
                    a0[l] += w02 * x.z; a0[l] += w03 * x.w;
                    a1[l] += w10 * x.x; a1[l] += w11 * x.y;
                    a1[l] += w12 * x.z; a1[l] += w13 * x.w;
                }
            }
        } else {
            #pragma unroll 4
            for (int kk = 0; kk < KPG; kk += 4) {
                float w0q[4], w1q[4];
                #pragma unroll
                for (int q = 0; q < 4; ++q) {
                    const int k = j * KPG + kk + q;
                    w0q[q] = (k < K) ? WT[(long)k * OUT + n0]
                           : (k < K + 16) ? ald(&Dj[(k - K) * OUT + n0]) : 0.f;
                    w1q[q] = (k < K) ? WT[(long)k * OUT + n0 + 32]
                           : (k < K + 16) ? ald(&Dj[(k - K) * OUT + n0 + 32]) : 0.f;
                }
                #pragma unroll
                for (int l = 0; l < 8; ++l) {
                    const float4 x = *(const float4*)&xb[l * PW + kk];
                    a0[l] += w0q[0] * x.x; a0[l] += w0q[1] * x.y;
                    a0[l] += w0q[2] * x.z; a0[l] += w0q[3] * x.w;
                    a1[l] += w1q[0] * x.x; a1[l] += w1q[1] * x.y;
                    a1[l] += w1q[2] * x.z; a1[l] += w1q[3] * x.w;
                }
            }
        }
        __syncthreads();   // sP region free (vs sA / previous reduce reads)
        #pragma unroll
        for (int l = 0; l < 8; ++l) {
            sP[(j * 64 + r) * 9 + l]      = a0[l];
            sP[(j * 64 + 32 + r) * 9 + l] = a1[l];
        }
        __syncthreads();
        {   // 16-way reduce: exactly one output per thread (64 n x 8 l = 512)
            const int nn = tid >> 3, ll = tid & 7;
            float v = 0.f;
            #pragma unroll
            for (int q = 0; q < 16; ++q) v += sP[(q * 64 + nn) * 9 + ll];
            const int n = nc * 64 + nn;
            if (BIAS) v += bias[n];
            if (RELU) v = fmaxf(v, 0.f);
            sactN[ll * PW + n] = v;
        }
    }
    __syncthreads();
    // zero-pad cols [OUT+16, PW) of the output for the next consumer
    constexpr int ZC = PW - (OUT + 16);
    for (int f = tid; f < 8 * ZC; f += 512) {
        const int l = f / ZC, c = f - l * ZC;
        sactN[l * PW + OUT + 16 + c] = 0.f;
    }
    __syncthreads();
}

// ---------------------------------------------------------------------------
// Phase-2: test forward + loss, fully block-local. grid 256 blocks of 512.
// ---------------------------------------------------------------------------
__global__ __launch_bounds__(512, 1) void k_p2(
    const float* __restrict__ tx, const float* __restrict__ tex,
    const float* __restrict__ tey, const float* __restrict__ teg,
    const float* __restrict__ b1v, const float* __restrict__ b2v,
    const float* __restrict__ b3v,
    const float* __restrict__ WT1, const float* __restrict__ WT2,
    const float* __restrict__ WT3, const float* __restrict__ WT4,
    const float* __restrict__ H1, const float* __restrict__ H2,
    const float* __restrict__ HG,
    const float* __restrict__ D1, const float* __restrict__ D2,
    const float* __restrict__ D3, const float* __restrict__ D4,
    const float* __restrict__ loglr, float* __restrict__ outp)
{
    const int tid = threadIdx.x;
    const int b = blockIdx.x >> 4;
    const int l0 = (blockIdx.x & 15) * 8;
    const float lr = expf(loglr[0]);

    __shared__ __align__(16) float pool[18624];   // ~74.5 KB
    float* a0  = pool;            // act buffers [8][PW]
    float* a1  = pool + 4704;     // 8*588
    float* sWA = pool + 9408;     // scratch: sA [16][K+4] / sP [16][64][9]

    const float* txb = tx + b * (TT * XX);
    const float* H1b = H1 + b * (TT * HH);
    const float* H2b = H2 + b * (TT * HH);
    const float* HGb = HG + b * (TT * HH);
    const float* D1b = D1 + b * (TT * HH);
    const float* D2b = D2 + b * (TT * HH);
    const float* D3b = D3 + b * (TT * HH);
    const float* D4b = D4 + b * (TT * YY);

    // stage tex rows (zero-padded to PW)
    for (int f = tid; f < 8 * PW; f += 512) {
        const int l = f / PW, c = f - l * PW;
        a0[f] = (c < XX) ? tex[((long)b * LL + l0 + l) * XX + c] : 0.f;
    }
    __syncthreads();

    p2_layer<XX, HH, true, true, true>(WT1, b1v, D1b, txb, lr, a0, a1, sWA);
    p2_layer<HH, HH, true, true, true>(WT2, b2v, D2b, H1b, lr, a1, a0, sWA);
    p2_layer<HH, HH, true, true, true>(WT3, b3v, D3b, H2b, lr, a0, a1, sWA);

    // gate act3 with test_gate
    for (int f = tid; f < 8 * HH; f += 512) {
        const int l = f >> 9, k = f & 511;
        a1[l * PW + k] *= teg[((long)b * LL + l0 + l) * HH + k];
    }
    __syncthreads();

    p2_layer<HH, YY, false, false, false>(WT4, nullptr, D4b, HGb, lr, a1, a0, sWA);

    // logits out
    for (int f = tid; f < 8 * YY; f += 512) {
        const int l = f >> 8, y = f & 255;
        outp[4097 + ((long)(b * LL + l0 + l)) * YY + y] = a0[l * PW + y];
    }
    // loss + evaluation (first 256 threads: 8 l x 32 lanes)
    if (tid < 256) {
        const int l = tid >> 5, kk = tid & 31;
        float a = 0.f;
        #pragma unroll
        for (int jj = 0; jj < 8; ++jj) {
            const int y = kk * 8 + jj;
            const float d = a0[l * PW + y] -
                            tey[((long)b * LL + l0 + l) * YY + y];
            a += d * d;
        }
        a += __shfl_xor(a, 1);
        a += __shfl_xor(a, 2);
        a += __shfl_xor(a, 4);
        a += __shfl_xor(a, 8);
        a += __shfl_xor(a, 16);
        if (kk == 0) {
            const float v = a * (1.0f / YY);
            const int idx = b * LL + l0 + l;
            outp[idx] = v;
            outp[2049 + idx] = v;
        }
    }
}

// ---------------------------------------------------------------------------
extern "C" void kernel_launch(void* const* d_in, const int* in_sizes, int n_in,
                              void* d_out, int out_size, void* d_ws, size_t ws_size,
                              hipStream_t stream)
{
    const float* tx    = (const float*)d_in[0];   // train_x  [B][T][X]
    const float* ty    = (const float*)d_in[1];   // train_y  [B][T][Y]
    const float* tex   = (const float*)d_in[2];   // test_x   [B][L][X]
    const float* tey   = (const float*)d_in[3];   // test_y   [B][L][Y]
    const float* tg    = (const float*)d_in[4];   // train_gate [B][T][H]
    const float* teg   = (const float*)d_in[5];   // test_gate  [B][L][H]
    const float* W1    = (const float*)d_in[6];
    const float* b1    = (const float*)d_in[7];
    const float* W2    = (const float*)d_in[8];
    const float* b2    = (const float*)d_in[9];
    const float* W3    = (const float*)d_in[10];
    const float* b3    = (const float*)d_in[11];
    const float* W4    = (const float*)d_in[12];
    const float* loglr = (const float*)d_in[13];

    float* out = (float*)d_out;
    float* ws  = (float*)d_ws;

    // workspace layout (floats). H1..D4 are contiguous (851968 words) and
    // sentinel-prefilled by k_tr. cpart lives in the unused ActB region.
    float* H1     = ws + 135168;        // 131072
    float* H2     = ws + 266240;        // 131072
    float* HG     = ws + 397312;        // 131072
    float* D1     = ws + 528384;        // 131072
    float* D2     = ws + 659456;        // 131072
    float* D3     = ws + 790528;        // 131072
    float* D4     = ws + 921600;        // 65536
    float* ActA   = ws + 1024000;       // holds WT1..WT4
    float* WT1    = ActA;               // [256][512] = 131072
    float* WT2    = ActA + 131072;      // [512][512] = 262144
    float* WT3    = ActA + 393216;      // [512][512] = 262144
    float* WT4    = ActA + 655360;      // [512][256] = 131072
    float* cpart  = ws + 2072576;       // 16 tasks x 96 stages x 256 = 393216

    // Transpose weights + sentinel-prefill handoff buffers + inner_lr.
    k_tr<<<192, 256, 0, stream>>>(W1, W2, W3, W4, WT1, WT2, WT3, WT4, loglr,
                                  out, (unsigned*)H1, (unsigned*)cpart);

    // 16-step MAML inner loop (persistent, barrier-free sentinel data-flow).
    k_inner<<<TB * 16, 256, 0, stream>>>(tx, ty, tg, b1, b2, b3, W2, W3, W4,
                                         WT1, WT2, WT3, WT4, loglr,
                                         H1, H2, HG, D1, D2, D3, D4, cpart);

    // Phase 2: test-set forward + loss, one block-local dispatch (512 thr).
    k_p2<<<TB * 16, 512, 0, stream>>>(tx, tex, tey, teg, b1, b2, b3,
                                      WT1, WT2, WT3, WT4,
                                      H1, H2, HG, D1, D2, D3, D4,
                                      loglr, out);
}

// Round 15
// 483.285 us; speedup vs baseline: 2.4506x; 1.0262x over previous
//
#include <hip/hip_runtime.h>
#include <math.h>

// Problem dims
#define TB 16   // batch (tasks)
#define TT 16   // train steps
#define LL 128  // test length
#define XX 256  // x dim
#define HH 512  // hidden
#define YY 256  // y dim

#define PW 588  // phase-2 act row pitch
#define SENTU 0xFFC0DEADu   // sentinel: NaN payload, never produced by finite math

typedef unsigned long long u64;

// ---------------------------------------------------------------------------
// Cross-block primitives (all agent-scope, coherent-point).
// WRITE: no-return atomic exchange — executes at the coherent point, no
//   response wait. Safe because readers poll the DATA ITSELF (sentinel
//   protocol) — no separate flag whose ordering could race (the R8-R10 bug).
// READ: atomic loads (bypass L1/L2).
// ---------------------------------------------------------------------------
__device__ __forceinline__ void axs(float* p, float v) {
    (void)__hip_atomic_exchange(p, v, __ATOMIC_RELAXED, __HIP_MEMORY_SCOPE_AGENT);
}
__device__ __forceinline__ float ald(const float* p) {
    return __hip_atomic_load(p, __ATOMIC_RELAXED, __HIP_MEMORY_SCOPE_AGENT);
}
__device__ __forceinline__ unsigned aldu(const unsigned* p) {
    return __hip_atomic_load(p, __ATOMIC_RELAXED, __HIP_MEMORY_SCOPE_AGENT);
}
__device__ __forceinline__ u64 ald8(const u64* p) {
    return __hip_atomic_load(p, __ATOMIC_RELAXED, __HIP_MEMORY_SCOPE_AGENT);
}

// Partial dots of fresh slice (sout) against own LDS history rows s <= tmax.
__device__ __forceinline__ void partials32L(const float* hist, int tmax,
                                            float* cpw, int blk, const float* sout) {
    const int tid = threadIdx.x;
    const int s2 = tid >> 4, i = tid & 15;
    float pp = 0.f;
    const bool act = (s2 <= tmax);
    if (act) {
        pp = hist[s2 * 32 + 2 * i] * sout[2 * i] +
             hist[s2 * 32 + 2 * i + 1] * sout[2 * i + 1];
    }
    pp += __shfl_xor(pp, 1);
    pp += __shfl_xor(pp, 2);
    pp += __shfl_xor(pp, 4);
    pp += __shfl_xor(pp, 8);
    if (act && i == 0) axs(&cpw[s2 * 16 + blk], pp);
}

__device__ __forceinline__ void partials16L(const float* hist, int tmax,
                                            float* cpw, int blk, const float* sout) {
    const int tid = threadIdx.x;
    const int s2 = tid >> 4, i = tid & 15;
    float pp = 0.f;
    const bool act = (s2 <= tmax);
    if (act) pp = hist[s2 * 16 + i] * sout[i];
    pp += __shfl_xor(pp, 1);
    pp += __shfl_xor(pp, 2);
    pp += __shfl_xor(pp, 4);
    pp += __shfl_xor(pp, 8);
    if (act && i == 0) axs(&cpw[s2 * 16 + blk], pp);
}

// ---------------------------------------------------------------------------
// One phase-1 stage. MODE: 0=F2 1=F3 2=F4 3=B4 4=B3 5=B2(+h1_{t+1}).
// Barrier-free; BATCHED polling (R14-proven).
// ---------------------------------------------------------------------------
template <int MODE>
__device__ __forceinline__ void do_stage(
    int t, float lr, int base, int base16, int blk,
    const float* __restrict__ M, const float* __restrict__ src,
    float* __restrict__ dst, float* __restrict__ dst2,
    const float* __restrict__ tyb, const float* __restrict__ tgb, float rbias,
    float* __restrict__ cw, const float* __restrict__ crd,
    float* s_v, float* sp, float* sout, float* s_c,
    float* hcorr, float* hpart, float* hself,
    float* hD1v, float* hZ1v, float* sG1v)
{
    const int tid = threadIdx.x;
    constexpr int ROWS = (MODE == 2) ? 16 : 32;
    constexpr int G = 256 / ROWS;
    constexpr int KTOT = (MODE == 3) ? 256 : 512;
    constexpr int KPG = KTOT / G;
    constexpr int LD = (MODE == 2) ? YY : HH;

    const int r = tid & (ROWS - 1);
    const int j = tid / ROWS;

    // ---- weight prefetch (issues before the polls; overlaps waiting) ----
    const float* col = M + (j * KPG) * LD + r;
    float wreg[KPG];
    #pragma unroll
    for (int k = 0; k < KPG; ++k) wreg[k] = col[k * LD];

    // ---- combined batched poll: coefficients + fresh vector ----
    constexpr float P1 = (MODE == 0 || MODE == 1) ? 1.0f : 0.0f;
    constexpr int NF = (MODE == 3) ? YY : HH;
    {
        const int cs = tid >> 3, cj = tid & 7;
        const bool haveC = (tid < 128) && (cs < t);
        const unsigned* cp = (const unsigned*)(crd + cs * 16 + 2 * cj);
        const unsigned* vp = (const unsigned*)src;
        unsigned c0 = 0u, c1 = 0u, v1 = 0u;
        // issue all loads back-to-back (independent -> 1 RT)
        unsigned v0 = aldu(vp + tid);
        if (NF == 512) v1 = aldu(vp + tid + 256);
        if (haveC) { c0 = aldu(cp); c1 = aldu(cp + 1); }
        while ((v0 == SENTU) | ((NF == 512) & (v1 == SENTU)) |
               (haveC & ((c0 == SENTU) | (c1 == SENTU)))) {
            __builtin_amdgcn_s_sleep(1);
            if (v0 == SENTU) v0 = aldu(vp + tid);
            if (NF == 512 && v1 == SENTU) v1 = aldu(vp + tid + 256);
            if (haveC && c0 == SENTU) c0 = aldu(cp);
            if (haveC && c1 == SENTU) c1 = aldu(cp + 1);
        }
        s_v[tid] = __uint_as_float(v0);
        if (NF == 512) s_v[tid + 256] = __uint_as_float(v1);
        if (tid < 128) {
            float v = haveC ? (__uint_as_float(c0) + __uint_as_float(c1)) : 0.f;
            v += __shfl_xor(v, 1);
            v += __shfl_xor(v, 2);
            v += __shfl_xor(v, 4);
            if (cj == 0) s_c[cs] = lr * (v + P1);
        }
    }
    __syncthreads();

    // ---- matvec: registers x LDS ----
    float a = 0.f;
    const float* vv = s_v + j * KPG;
    #pragma unroll
    for (int k = 0; k < KPG; ++k) a += wreg[k] * vv[k];
    const int lane = tid & 63, w = tid >> 6;
    float sres = 0.f;
    if constexpr (ROWS == 32) {
        a += __shfl_xor(a, 32);
        if (lane < 32) sp[w * 32 + lane] = a;
        __syncthreads();
        if (tid < 32) sres = sp[tid] + sp[32 + tid] + sp[64 + tid] + sp[96 + tid];
    } else {
        a += __shfl_xor(a, 16);
        a += __shfl_xor(a, 32);
        if (lane < 16) sp[w * 16 + lane] = a;
        __syncthreads();
        if (tid < 16) sres = sp[tid] + sp[16 + tid] + sp[32 + tid] + sp[48 + tid];
    }

    // ---- epilogue (LDS history only) ----
    if (tid < ROWS) {
        float corr = 0.f;
        for (int s = 0; s < t; ++s) corr += hcorr[s * ROWS + tid] * s_c[s];
        if constexpr (MODE == 5) {
            const float dz = (sres - corr) * ((hcorr[t * 32 + tid] > 0.f) ? 1.f : 0.f);
            axs(dst + t * HH + base + tid, dz);
            hD1v[t * 32 + tid] = dz;
            if (t + 1 < TT) {
                float cr = dz * sG1v[t * 16 + (t + 1)];
                for (int s = 0; s < t; ++s)
                    cr += hD1v[s * 32 + tid] * sG1v[s * 16 + (t + 1)];
                const float h1n = fmaxf(hZ1v[(t + 1) * 32 + tid] - lr * cr, 0.f);
                axs(dst2 + (t + 1) * HH + base + tid, h1n);
                hself[(t + 1) * 32 + tid] = h1n;
                sout[tid] = h1n;
            }
        } else {
            float v;
            if constexpr (MODE == 0)
                v = fmaxf(sres + rbias - corr, 0.f);
            else if constexpr (MODE == 1)
                v = fmaxf(sres + rbias - corr, 0.f) * tgb[t * HH + base + tid];
            else if constexpr (MODE == 2)
                v = (sres - corr - tyb[t * YY + base16 + tid]) * (2.0f / YY);
            else if constexpr (MODE == 3)
                v = (sres - corr) * tgb[t * HH + base + tid] *
                    ((hcorr[t * 32 + tid] > 0.f) ? 1.f : 0.f);
            else
                v = (sres - corr) * ((hcorr[t * 32 + tid] > 0.f) ? 1.f : 0.f);
            if constexpr (MODE == 2) axs(dst + t * YY + base16 + tid, v);
            else                     axs(dst + t * HH + base + tid, v);
            hself[t * ROWS + tid] = v;
            sout[tid] = v;
        }
    }
    __syncthreads();

    // ---- partials for next stage's coefficients (own region, write-once) ----
    const int tmax = (MODE == 5) ? ((t + 1 < TT) ? t : -1) : (t - 1);
    if constexpr (MODE == 2) partials16L(hpart, tmax, cw, blk, sout);
    else                     partials32L(hpart, tmax, cw, blk, sout);
    __syncthreads();   // LDS reuse safety for next stage
}

// ---------------------------------------------------------------------------
// Transpose W1..W4 (64x64 tiles), sentinel-prefill handoff buffers, inner_lr.
// grid: 192 blocks of 256
// ---------------------------------------------------------------------------
__global__ __launch_bounds__(256) void k_tr(
    const float* __restrict__ W1, const float* __restrict__ W2,
    const float* __restrict__ W3, const float* __restrict__ W4,
    float* __restrict__ WT1, float* __restrict__ WT2,
    float* __restrict__ WT3, float* __restrict__ WT4,
    const float* __restrict__ loglr, float* __restrict__ out,
    unsigned* __restrict__ hist0, unsigned* __restrict__ cpart0)
{
    const int tid = threadIdx.x;
    int bid = blockIdx.x;
    if (blockIdx.x == 0 && tid == 0) out[2048] = expf(loglr[0]);

    // Sentinel-prefill: histories (851968 words, contiguous) + cpart (393216).
    {
        const int gt = blockIdx.x * 256 + tid;       // 49152 threads
        for (long i = gt; i < 851968; i += 192 * 256) hist0[i] = SENTU;
        for (long i = gt; i < 393216; i += 192 * 256) cpart0[i] = SENTU;
    }

    const float* src; float* dst; int R, C;
    if (bid < 32)       { src = W1; dst = WT1; R = 512; C = 256; }
    else if (bid < 96)  { src = W2; dst = WT2; R = 512; C = 512; bid -= 32; }
    else if (bid < 160) { src = W3; dst = WT3; R = 512; C = 512; bid -= 96; }
    else                { src = W4; dst = WT4; R = 256; C = 512; bid -= 160; }
    const int tilesC = C >> 6;
    const int i0 = (bid / tilesC) * 64, j0 = (bid % tilesC) * 64;

    __shared__ float sm[64][65];
    #pragma unroll
    for (int rep = 0; rep < 16; ++rep) {
        const int flat = rep * 256 + tid;
        const int r = flat >> 6, c = flat & 63;
        sm[r][c] = src[(i0 + r) * C + j0 + c];
    }
    __syncthreads();
    #pragma unroll
    for (int rep = 0; rep < 16; ++rep) {
        const int flat = rep * 256 + tid;
        const int c = flat >> 6, r = flat & 63;
        dst[(j0 + c) * R + i0 + r] = sm[r][c];
    }
}

// ---------------------------------------------------------------------------
// Persistent inner loop, barrier-free (sentinel data-flow). 256 blocks of 256;
// 16 blocks/task, 32 rows/block. Every cross-block word is write-once.
// ---------------------------------------------------------------------------
__global__ __launch_bounds__(256, 1) void k_inner(
    const float* __restrict__ tx, const float* __restrict__ ty, const float* __restrict__ tg,
    const float* __restrict__ b1v, const float* __restrict__ b2v, const float* __restrict__ b3v,
    const float* __restrict__ W2, const float* __restrict__ W3, const float* __restrict__ W4,
    const float* __restrict__ WT1, const float* __restrict__ WT2, const float* __restrict__ WT3,
    const float* __restrict__ WT4, const float* __restrict__ loglr,
    float* __restrict__ H1, float* __restrict__ H2, float* __restrict__ HG,
    float* __restrict__ D1, float* __restrict__ D2, float* __restrict__ D3, float* __restrict__ D4,
    float* __restrict__ cpart)
{
    const int tid = threadIdx.x;
    const int lane = tid & 63, w = tid >> 6;
    const int g = blockIdx.x;
    const int b = g >> 4;
    const int blk = ((g & 7) << 1) | ((g >> 3) & 1);   // XCD-local weight rows
    const int base = blk * 32, base16 = blk * 16;
    const float lr = expf(loglr[0]);

    const float* txb = tx + b * (TT * XX);
    const float* tyb = ty + b * (TT * YY);
    const float* tgb = tg + b * (TT * HH);
    float* H1b = H1 + b * (TT * HH);
    float* H2b = H2 + b * (TT * HH);
    float* HGb = HG + b * (TT * HH);
    float* D1b = D1 + b * (TT * HH);
    float* D2b = D2 + b * (TT * HH);
    float* D3b = D3 + b * (TT * HH);
    float* D4b = D4 + b * (TT * YY);
    float* creg = cpart + (long)b * 96 * 256;   // per-task: 96 stage regions

    __shared__ float s_x[16 * 260];  // P0 only
    __shared__ float spz[2176];      // P0 only
    __shared__ __align__(16) float s_v[HH];
    __shared__ float sp[128];
    __shared__ float sout[32];
    __shared__ float s_c[16];
    // Block-private history (own 32/16-row slices), LDS-resident:
    __shared__ float hH1[TT * 32], hH2[TT * 32], hHG[TT * 32];
    __shared__ float hD1[TT * 32], hD2[TT * 32], hD3[TT * 32];
    __shared__ float hD4[TT * 16];
    __shared__ float hZ1[TT * 32];
    __shared__ float sG1[TT * 16];

    const float rb2 = (tid < 32) ? b2v[base + tid] : 0.f;
    const float rb3 = (tid < 32) ? b3v[base + tid] : 0.f;

    // ---------------- P0: Z1base (LDS), G1 (LDS, replicated), H1[0] ----------
    {
        const float4* src4 = (const float4*)txb;   // 1024 float4
        #pragma unroll
        for (int q = 0; q < 4; ++q) {
            const int idx = q * 256 + tid;
            const int tt = idx >> 6, k4 = idx & 63;
            *(float4*)&s_x[tt * 260 + k4 * 4] = src4[idx];
        }
    }
    __syncthreads();
    {
        const int r = tid & 31, j = tid >> 5;
        float acc[16];
        #pragma unroll
        for (int tt = 0; tt < 16; ++tt) acc[tt] = 0.f;
        const float* col = WT1 + (j * 32) * HH + base + r;
        #pragma unroll 4
        for (int kk = 0; kk < 32; ++kk) {
            const float wv = col[kk * HH];
            const int k = j * 32 + kk;
            #pragma unroll
            for (int tt = 0; tt < 16; ++tt) acc[tt] += wv * s_x[tt * 260 + k];
        }
        #pragma unroll
        for (int tt = 0; tt < 16; ++tt) {
            float a = acc[tt] + __shfl_xor(acc[tt], 32);
            if (lane < 32) spz[w * 544 + lane * 17 + tt] = a;
        }
        __syncthreads();
        const int rr = tid & 31, tp = tid >> 5;
        #pragma unroll
        for (int q = 0; q < 2; ++q) {
            const int tt = tp * 2 + q;
            const int row = base + rr;
            float v = spz[rr * 17 + tt] + spz[544 + rr * 17 + tt] +
                      spz[1088 + rr * 17 + tt] + spz[1632 + rr * 17 + tt];
            v += b1v[row];
            hZ1[tt * 32 + rr] = v;
            if (tt == 0) {
                const float h = fmaxf(v, 0.f);
                hH1[rr] = h;
                axs(&H1b[row], h);   // self-announces to F2@t=0 pollers
            }
        }
    }
    {   // Gram matrix, replicated per block
        const int ss = tid >> 4, uu = tid & 15;
        float a = 0.f;
        for (int k = 0; k < 256; ++k) a += s_x[ss * 260 + k] * s_x[uu * 260 + k];
        sG1[ss * 16 + uu] = a + 1.0f;
    }
    __syncthreads();

    // ---------------- Phase 1: 16 SGD steps x 6 stages, barrier-free --------
    int k = 0;
    #pragma unroll 1
    for (int t = 0; t < TT; ++t) {
        do_stage<0>(t, lr, base, base16, blk, WT2 + base, H1b + t * HH,
                    H2b, nullptr, tyb, tgb, rb2,
                    creg + (long)k * 256, creg + (long)(k ? k - 1 : 0) * 256,
                    s_v, sp, sout, s_c, hD2, hH2, hH2, hD1, hZ1, sG1);
        ++k;
        do_stage<1>(t, lr, base, base16, blk, WT3 + base, H2b + t * HH,
                    HGb, nullptr, tyb, tgb, rb3,
                    creg + (long)k * 256, creg + (long)(k - 1) * 256,
                    s_v, sp, sout, s_c, hD3, hHG, hHG, hD1, hZ1, sG1);
        ++k;
        do_stage<2>(t, lr, base, base16, blk, WT4 + base16, HGb + t * HH,
                    D4b, nullptr, tyb, tgb, 0.f,
                    creg + (long)k * 256, creg + (long)(k - 1) * 256,
                    s_v, sp, sout, s_c, hD4, hD4, hD4, hD1, hZ1, sG1);
        ++k;
        do_stage<3>(t, lr, base, base16, blk, W4 + base, D4b + t * YY,
                    D3b, nullptr, tyb, tgb, 0.f,
                    creg + (long)k * 256, creg + (long)(k - 1) * 256,
                    s_v, sp, sout, s_c, hHG, hD3, hD3, hD1, hZ1, sG1);
        ++k;
        do_stage<4>(t, lr, base, base16, blk, W3 + base, D3b + t * HH,
                    D2b, nullptr, tyb, tgb, 0.f,
                    creg + (long)k * 256, creg + (long)(k - 1) * 256,
                    s_v, sp, sout, s_c, hH2, hD2, hD2, hD1, hZ1, sG1);
        ++k;
        do_stage<5>(t, lr, base, base16, blk, W2 + base, D2b + t * HH,
                    D1b, H1b, tyb, tgb, 0.f,
                    creg + (long)k * 256, creg + (long)(k - 1) * 256,
                    s_v, sp, sout, s_c, hH1, hH1, hH1, hD1, hZ1, sG1);
        ++k;
    }
}

// ---------------------------------------------------------------------------
// Phase-2 fused layer, 4 test rows per block, 512 threads.
// GEMM: r = tid&127 (2 n: r, r+128 within a 256-n chunk), j = tid>>7 (4-way
// k-split, KPG = KE/4) — 4x fewer syncs/reduces than the 16-way R14 version,
// 4x longer serial k-run per thread (ILP over L2/HBM weight loads).
// ---------------------------------------------------------------------------
template <int K, int OUT, bool RELU, bool BIAS, bool PLUSONE>
__device__ __forceinline__ void p2_layer(
    const float* __restrict__ WT,      // [K][OUT]
    const float* __restrict__ bias,    // [OUT] or null
    const float* __restrict__ Dj,      // [16][OUT]  (k_inner output)
    const float* __restrict__ Asrc,    // [16][K]    (k_inner output / input)
    float lr, float* sact, float* sactN, float* sWA)
{
    constexpr int KE = (K + 16 + 63) & ~63;   // 320 / 576
    constexpr int KPG = KE / 4;               // 80 / 144 (multiple of 4)
    constexpr int SAP = K + 4;                // sA pitch (bank spread)
    const int tid = threadIdx.x;

    // ---- stage A rows into LDS (batched coherent 64-bit atomic loads) ----
    float* sA = sWA;   // [16][SAP]
    {
        constexpr int TOT = 16 * (K / 2);     // u64 count: 4096 / 2048
        constexpr int PER = TOT / 512;        // 8 / 4
        u64 tmp[PER];
        #pragma unroll
        for (int q = 0; q < PER; ++q)
            tmp[q] = ald8((const u64*)Asrc + tid + q * 512);
        #pragma unroll
        for (int q = 0; q < PER; ++q) {
            const int idx = tid + q * 512;
            const int s = idx / (K / 2), c = idx - s * (K / 2);
            *(u64*)(sA + s * SAP + c * 2) = tmp[q];
        }
    }
    __syncthreads();

    // ---- ip[s][l] -> sact[l][K+s] = -lr*(A_s . act_l + plus1) ----
    // 16 s x 4 l x 8 q (q-interleaved float4s -> bank spread).
    {
        const int s = tid >> 5, lq = tid & 31;
        const int l = lq >> 3, q = lq & 7;
        const float4* av = (const float4*)(sA + s * SAP);
        const float4* xv = (const float4*)(sact + l * PW);
        float a = 0.f;
        for (int k = 0; k < K / 32; ++k) {
            const float4 u = av[k * 8 + q];
            const float4 x = xv[k * 8 + q];
            a += u.x * x.x + u.y * x.y + u.z * x.z + u.w * x.w;
        }
        a += __shfl_xor(a, 1);
        a += __shfl_xor(a, 2);
        a += __shfl_xor(a, 4);
        if (q == 0) sact[l * PW + K + s] = -lr * (a + (PLUSONE ? 1.f : 0.f));
    }
    __syncthreads();

    // ---- GEMM ----
    float* sP = sWA;   // [4][256][9] partials (sA dead after ip step)
    const int r = tid & 127, j = tid >> 7;   // j in 0..3
    const float* xb = sact + j * KPG;
    for (int nc = 0; nc < OUT / 256; ++nc) {
        const int n0 = nc * 256 + r;
        float a0[4], a1[4];
        #pragma unroll
        for (int l = 0; l < 4; ++l) { a0[l] = 0.f; a1[l] = 0.f; }
        if ((j + 1) * KPG <= K) {
            const float* c0 = WT + (long)(j * KPG) * OUT + n0;
            #pragma unroll 4
            for (int kk = 0; kk < KPG; kk += 4) {
                float w00, w01, w02, w03, w10, w11, w12, w13;
                w00 = c0[(long)(kk + 0) * OUT]; w10 = c0[(long)(kk + 0) * OUT + 128];
                w01 = c0[(long)(kk + 1) * OUT]; w11 = c0[(long)(kk + 1) * OUT + 128];
                w02 = c0[(long)(kk + 2) * OUT]; w12 = c0[(long)(kk + 2) * OUT + 128];
                w03 = c0[(long)(kk + 3) * OUT]; w13 = c0[(long)(kk + 3) * OUT + 128];
                #pragma unroll
                for (int l = 0; l < 4; ++l) {
                    const float4 x = *(const float4*)&xb[l * PW + kk];
                    a0[l] += w00 * x.x; a0[l] += w01 * x.y;
                    a0[l] += w02 * x.z; a0[l] += w03 * x.w;
                    a1[l] += w10 * x.x; a1[l] += w11 * x.y;
                    a1[l] += w12 * x.z; a1[l] += w13 * x.w;
                }
            }
        } else {
            #pragma unroll 4
            for (int kk = 0; kk < KPG; kk += 4) {
                float w0q[4], w1q[4];
                #pragma unroll
                for (int q = 0; q < 4; ++q) {
                    const int k = j * KPG + kk + q;
                    w0q[q] = (k < K) ? WT[(long)k * OUT + n0]
                           : (k < K + 16) ? ald(&Dj[(k - K) * OUT + n0]) : 0.f;
                    w1q[q] = (k < K) ? WT[(long)k * OUT + n0 + 128]
                           : (k < K + 16) ? ald(&Dj[(k - K) * OUT + n0 + 128]) : 0.f;
                }
                #pragma unroll
                for (int l = 0; l < 4; ++l) {
                    const float4 x = *(const float4*)&xb[l * PW + kk];
                    a0[l] += w0q[0] * x.x; a0[l] += w0q[1] * x.y;
                    a0[l] += w0q[2] * x.z; a0[l] += w0q[3] * x.w;
                    a1[l] += w1q[0] * x.x; a1[l] += w1q[1] * x.y;
                    a1[l] += w1q[2] * x.z; a1[l] += w1q[3] * x.w;
                }
            }
        }
        __syncthreads();   // sP region free (vs sA / previous reduce reads)
        #pragma unroll
        for (int l = 0; l < 4; ++l) {
            sP[(j * 256 + r) * 9 + l]       = a0[l];
            sP[(j * 256 + 128 + r) * 9 + l] = a1[l];
        }
        __syncthreads();
        {   // 4-way reduce: 2 outputs per thread (256 n x 4 l = 1024)
            const int nn = tid >> 1, ll0 = (tid & 1) * 2;
            #pragma unroll
            for (int e = 0; e < 2; ++e) {
                const int ll = ll0 + e;
                float v = sP[(0 * 256 + nn) * 9 + ll] + sP[(1 * 256 + nn) * 9 + ll] +
                          sP[(2 * 256 + nn) * 9 + ll] + sP[(3 * 256 + nn) * 9 + ll];
                const int n = nc * 256 + nn;
                if (BIAS) v += bias[n];
                if (RELU) v = fmaxf(v, 0.f);
                sactN[ll * PW + n] = v;
            }
        }
    }
    __syncthreads();
    // zero-pad cols [OUT+16, PW) of the output for the next consumer
    constexpr int ZC = PW - (OUT + 16);
    for (int f = tid; f < 4 * ZC; f += 512) {
        const int l = f / ZC, c = f - l * ZC;
        sactN[l * PW + OUT + 16 + c] = 0.f;
    }
    __syncthreads();
}

// ---------------------------------------------------------------------------
// Phase-2: test forward + loss, fully block-local. grid 512 blocks of 512:
// block = (task b, 4 test rows) -> 2 blocks/CU (4 waves/SIMD) for latency
// hiding. LDS 55.7 KB/block. No atomics except coherent k_inner-data reads.
// ---------------------------------------------------------------------------
__global__ __launch_bounds__(512, 4) void k_p2(
    const float* __restrict__ tx, const float* __restrict__ tex,
    const float* __restrict__ tey, const float* __restrict__ teg,
    const float* __restrict__ b1v, const float* __restrict__ b2v,
    const float* __restrict__ b3v,
    const float* __restrict__ WT1, const float* __restrict__ WT2,
    const float* __restrict__ WT3, const float* __restrict__ WT4,
    const float* __restrict__ H1, const float* __restrict__ H2,
    const float* __restrict__ HG,
    const float* __restrict__ D1, const float* __restrict__ D2,
    const float* __restrict__ D3, const float* __restrict__ D4,
    const float* __restrict__ loglr, float* __restrict__ outp)
{
    const int tid = threadIdx.x;
    const int b = blockIdx.x >> 5;
    const int l0 = (blockIdx.x & 31) * 4;
    const float lr = expf(loglr[0]);

    __shared__ __align__(16) float pool[13920];   // 55.7 KB
    float* a0  = pool;            // act buffers [4][PW]
    float* a1  = pool + 2352;     // 4*588
    float* sWA = pool + 4704;     // scratch: sA [16][K+4] / sP [4][256][9]

    const float* txb = tx + b * (TT * XX);
    const float* H1b = H1 + b * (TT * HH);
    const float* H2b = H2 + b * (TT * HH);
    const float* HGb = HG + b * (TT * HH);
    const float* D1b = D1 + b * (TT * HH);
    const float* D2b = D2 + b * (TT * HH);
    const float* D3b = D3 + b * (TT * HH);
    const float* D4b = D4 + b * (TT * YY);

    // stage tex rows (zero-padded to PW)
    for (int f = tid; f < 4 * PW; f += 512) {
        const int l = f / PW, c = f - l * PW;
        a0[f] = (c < XX) ? tex[((long)b * LL + l0 + l) * XX + c] : 0.f;
    }
    __syncthreads();

    p2_layer<XX, HH, true, true, true>(WT1, b1v, D1b, txb, lr, a0, a1, sWA);
    p2_layer<HH, HH, true, true, true>(WT2, b2v, D2b, H1b, lr, a1, a0, sWA);
    p2_layer<HH, HH, true, true, true>(WT3, b3v, D3b, H2b, lr, a0, a1, sWA);

    // gate act3 with test_gate
    for (int f = tid; f < 4 * HH; f += 512) {
        const int l = f >> 9, k = f & 511;
        a1[l * PW + k] *= teg[((long)b * LL + l0 + l) * HH + k];
    }
    __syncthreads();

    p2_layer<HH, YY, false, false, false>(WT4, nullptr, D4b, HGb, lr, a1, a0, sWA);

    // logits out
    for (int f = tid; f < 4 * YY; f += 512) {
        const int l = f >> 8, y = f & 255;
        outp[4097 + ((long)(b * LL + l0 + l)) * YY + y] = a0[l * PW + y];
    }
    // loss + evaluation (first 128 threads: 4 l x 32 lanes)
    if (tid < 128) {
        const int l = tid >> 5, kk = tid & 31;
        float a = 0.f;
        #pragma unroll
        for (int jj = 0; jj < 8; ++jj) {
            const int y = kk * 8 + jj;
            const float d = a0[l * PW + y] -
                            tey[((long)b * LL + l0 + l) * YY + y];
            a += d * d;
        }
        a += __shfl_xor(a, 1);
        a += __shfl_xor(a, 2);
        a += __shfl_xor(a, 4);
        a += __shfl_xor(a, 8);
        a += __shfl_xor(a, 16);
        if (kk == 0) {
            const float v = a * (1.0f / YY);
            const int idx = b * LL + l0 + l;
            outp[idx] = v;
            outp[2049 + idx] = v;
        }
    }
}

// ---------------------------------------------------------------------------
extern "C" void kernel_launch(void* const* d_in, const int* in_sizes, int n_in,
                              void* d_out, int out_size, void* d_ws, size_t ws_size,
                              hipStream_t stream)
{
    const float* tx    = (const float*)d_in[0];   // train_x  [B][T][X]
    const float* ty    = (const float*)d_in[1];   // train_y  [B][T][Y]
    const float* tex   = (const float*)d_in[2];   // test_x   [B][L][X]
    const float* tey   = (const float*)d_in[3];   // test_y   [B][L][Y]
    const float* tg    = (const float*)d_in[4];   // train_gate [B][T][H]
    const float* teg   = (const float*)d_in[5];   // test_gate  [B][L][H]
    const float* W1    = (const float*)d_in[6];
    const float* b1    = (const float*)d_in[7];
    const float* W2    = (const float*)d_in[8];
    const float* b2    = (const float*)d_in[9];
    const float* W3    = (const float*)d_in[10];
    const float* b3    = (const float*)d_in[11];
    const float* W4    = (const float*)d_in[12];
    const float* loglr = (const float*)d_in[13];

    float* out = (float*)d_out;
    float* ws  = (float*)d_ws;

    // workspace layout (floats). H1..D4 are contiguous (851968 words) and
    // sentinel-prefilled by k_tr. cpart lives in the unused ActB region.
    float* H1     = ws + 135168;        // 131072
    float* H2     = ws + 266240;        // 131072
    float* HG     = ws + 397312;        // 131072
    float* D1     = ws + 528384;        // 131072
    float* D2     = ws + 659456;        // 131072
    float* D3     = ws + 790528;        // 131072
    float* D4     = ws + 921600;        // 65536
    float* ActA   = ws + 1024000;       // holds WT1..WT4
    float* WT1    = ActA;               // [256][512] = 131072
    float* WT2    = ActA + 131072;      // [512][512] = 262144
    float* WT3    = ActA + 393216;      // [512][512] = 262144
    float* WT4    = ActA + 655360;      // [512][256] = 131072
    float* cpart  = ws + 2072576;       // 16 tasks x 96 stages x 256 = 393216

    // Transpose weights + sentinel-prefill handoff buffers + inner_lr.
    k_tr<<<192, 256, 0, stream>>>(W1, W2, W3, W4, WT1, WT2, WT3, WT4, loglr,
                                  out, (unsigned*)H1, (unsigned*)cpart);

    // 16-step MAML inner loop (persistent, barrier-free sentinel data-flow).
    k_inner<<<TB * 16, 256, 0, stream>>>(tx, ty, tg, b1, b2, b3, W2, W3, W4,
                                         WT1, WT2, WT3, WT4, loglr,
                                         H1, H2, HG, D1, D2, D3, D4, cpart);

    // Phase 2: test-set forward + loss; 512 blocks of 512 (2 blocks/CU).
    k_p2<<<TB * 32, 512, 0, stream>>>(tx, tex, tey, teg, b1, b2, b3,
                                      WT1, WT2, WT3, WT4,
                                      H1, H2, HG, D1, D2, D3, D4,
                                      loglr, out);
}

// Round 16
// 382.724 us; speedup vs baseline: 3.0945x; 1.2628x over previous
//
#include <hip/hip_runtime.h>
#include <math.h>

// Problem dims
#define TB 16   // batch (tasks)
#define TT 16   // train steps
#define LL 128  // test length
#define XX 256  // x dim
#define HH 512  // hidden
#define YY 256  // y dim

#define PW 588  // phase-2 act row pitch
#define SENTU 0xFFC0DEADu   // sentinel: NaN payload, never produced by finite math

typedef unsigned long long u64;

// ---------------------------------------------------------------------------
// Cross-block primitives (all agent-scope, coherent-point).
// WRITE: no-return atomic exchange — executes at the coherent point, no
//   response wait. Safe because readers poll the DATA ITSELF (sentinel
//   protocol) — no separate flag whose ordering could race (the R8-R10 bug).
// READ: atomic loads (bypass L1/L2).
// ---------------------------------------------------------------------------
__device__ __forceinline__ void axs(float* p, float v) {
    (void)__hip_atomic_exchange(p, v, __ATOMIC_RELAXED, __HIP_MEMORY_SCOPE_AGENT);
}
__device__ __forceinline__ float ald(const float* p) {
    return __hip_atomic_load(p, __ATOMIC_RELAXED, __HIP_MEMORY_SCOPE_AGENT);
}
__device__ __forceinline__ unsigned aldu(const unsigned* p) {
    return __hip_atomic_load(p, __ATOMIC_RELAXED, __HIP_MEMORY_SCOPE_AGENT);
}
__device__ __forceinline__ u64 ald8(const u64* p) {
    return __hip_atomic_load(p, __ATOMIC_RELAXED, __HIP_MEMORY_SCOPE_AGENT);
}

// Partial dots of fresh slice (sout) against own LDS history rows s <= tmax.
__device__ __forceinline__ void partials32L(const float* hist, int tmax,
                                            float* cpw, int blk, const float* sout) {
    const int tid = threadIdx.x;
    const int s2 = tid >> 4, i = tid & 15;
    float pp = 0.f;
    const bool act = (s2 <= tmax);
    if (act) {
        pp = hist[s2 * 32 + 2 * i] * sout[2 * i] +
             hist[s2 * 32 + 2 * i + 1] * sout[2 * i + 1];
    }
    pp += __shfl_xor(pp, 1);
    pp += __shfl_xor(pp, 2);
    pp += __shfl_xor(pp, 4);
    pp += __shfl_xor(pp, 8);
    if (act && i == 0) axs(&cpw[s2 * 16 + blk], pp);
}

__device__ __forceinline__ void partials16L(const float* hist, int tmax,
                                            float* cpw, int blk, const float* sout) {
    const int tid = threadIdx.x;
    const int s2 = tid >> 4, i = tid & 15;
    float pp = 0.f;
    const bool act = (s2 <= tmax);
    if (act) pp = hist[s2 * 16 + i] * sout[i];
    pp += __shfl_xor(pp, 1);
    pp += __shfl_xor(pp, 2);
    pp += __shfl_xor(pp, 4);
    pp += __shfl_xor(pp, 8);
    if (act && i == 0) axs(&cpw[s2 * 16 + blk], pp);
}

// ---------------------------------------------------------------------------
// One phase-1 stage. MODE: 0=F2 1=F3 2=F4 3=B4 4=B3 5=B2(+h1_{t+1}).
// Barrier-free; BATCHED polling (R14-proven).
// ---------------------------------------------------------------------------
template <int MODE>
__device__ __forceinline__ void do_stage(
    int t, float lr, int base, int base16, int blk,
    const float* __restrict__ M, const float* __restrict__ src,
    float* __restrict__ dst, float* __restrict__ dst2,
    const float* __restrict__ tyb, const float* __restrict__ tgb, float rbias,
    float* __restrict__ cw, const float* __restrict__ crd,
    float* s_v, float* sp, float* sout, float* s_c,
    float* hcorr, float* hpart, float* hself,
    float* hD1v, float* hZ1v, float* sG1v)
{
    const int tid = threadIdx.x;
    constexpr int ROWS = (MODE == 2) ? 16 : 32;
    constexpr int G = 256 / ROWS;
    constexpr int KTOT = (MODE == 3) ? 256 : 512;
    constexpr int KPG = KTOT / G;
    constexpr int LD = (MODE == 2) ? YY : HH;

    const int r = tid & (ROWS - 1);
    const int j = tid / ROWS;

    // ---- weight prefetch (issues before the polls; overlaps waiting) ----
    const float* col = M + (j * KPG) * LD + r;
    float wreg[KPG];
    #pragma unroll
    for (int k = 0; k < KPG; ++k) wreg[k] = col[k * LD];

    // ---- combined batched poll: coefficients + fresh vector ----
    constexpr float P1 = (MODE == 0 || MODE == 1) ? 1.0f : 0.0f;
    constexpr int NF = (MODE == 3) ? YY : HH;
    {
        const int cs = tid >> 3, cj = tid & 7;
        const bool haveC = (tid < 128) && (cs < t);
        const unsigned* cp = (const unsigned*)(crd + cs * 16 + 2 * cj);
        const unsigned* vp = (const unsigned*)src;
        unsigned c0 = 0u, c1 = 0u, v1 = 0u;
        // issue all loads back-to-back (independent -> 1 RT)
        unsigned v0 = aldu(vp + tid);
        if (NF == 512) v1 = aldu(vp + tid + 256);
        if (haveC) { c0 = aldu(cp); c1 = aldu(cp + 1); }
        while ((v0 == SENTU) | ((NF == 512) & (v1 == SENTU)) |
               (haveC & ((c0 == SENTU) | (c1 == SENTU)))) {
            __builtin_amdgcn_s_sleep(1);
            if (v0 == SENTU) v0 = aldu(vp + tid);
            if (NF == 512 && v1 == SENTU) v1 = aldu(vp + tid + 256);
            if (haveC && c0 == SENTU) c0 = aldu(cp);
            if (haveC && c1 == SENTU) c1 = aldu(cp + 1);
        }
        s_v[tid] = __uint_as_float(v0);
        if (NF == 512) s_v[tid + 256] = __uint_as_float(v1);
        if (tid < 128) {
            float v = haveC ? (__uint_as_float(c0) + __uint_as_float(c1)) : 0.f;
            v += __shfl_xor(v, 1);
            v += __shfl_xor(v, 2);
            v += __shfl_xor(v, 4);
            if (cj == 0) s_c[cs] = lr * (v + P1);
        }
    }
    __syncthreads();

    // ---- matvec: registers x LDS ----
    float a = 0.f;
    const float* vv = s_v + j * KPG;
    #pragma unroll
    for (int k = 0; k < KPG; ++k) a += wreg[k] * vv[k];
    const int lane = tid & 63, w = tid >> 6;
    float sres = 0.f;
    if constexpr (ROWS == 32) {
        a += __shfl_xor(a, 32);
        if (lane < 32) sp[w * 32 + lane] = a;
        __syncthreads();
        if (tid < 32) sres = sp[tid] + sp[32 + tid] + sp[64 + tid] + sp[96 + tid];
    } else {
        a += __shfl_xor(a, 16);
        a += __shfl_xor(a, 32);
        if (lane < 16) sp[w * 16 + lane] = a;
        __syncthreads();
        if (tid < 16) sres = sp[tid] + sp[16 + tid] + sp[32 + tid] + sp[48 + tid];
    }

    // ---- epilogue (LDS history only) ----
    if (tid < ROWS) {
        float corr = 0.f;
        for (int s = 0; s < t; ++s) corr += hcorr[s * ROWS + tid] * s_c[s];
        if constexpr (MODE == 5) {
            const float dz = (sres - corr) * ((hcorr[t * 32 + tid] > 0.f) ? 1.f : 0.f);
            axs(dst + t * HH + base + tid, dz);
            hD1v[t * 32 + tid] = dz;
            if (t + 1 < TT) {
                float cr = dz * sG1v[t * 16 + (t + 1)];
                for (int s = 0; s < t; ++s)
                    cr += hD1v[s * 32 + tid] * sG1v[s * 16 + (t + 1)];
                const float h1n = fmaxf(hZ1v[(t + 1) * 32 + tid] - lr * cr, 0.f);
                axs(dst2 + (t + 1) * HH + base + tid, h1n);
                hself[(t + 1) * 32 + tid] = h1n;
                sout[tid] = h1n;
            }
        } else {
            float v;
            if constexpr (MODE == 0)
                v = fmaxf(sres + rbias - corr, 0.f);
            else if constexpr (MODE == 1)
                v = fmaxf(sres + rbias - corr, 0.f) * tgb[t * HH + base + tid];
            else if constexpr (MODE == 2)
                v = (sres - corr - tyb[t * YY + base16 + tid]) * (2.0f / YY);
            else if constexpr (MODE == 3)
                v = (sres - corr) * tgb[t * HH + base + tid] *
                    ((hcorr[t * 32 + tid] > 0.f) ? 1.f : 0.f);
            else
                v = (sres - corr) * ((hcorr[t * 32 + tid] > 0.f) ? 1.f : 0.f);
            if constexpr (MODE == 2) axs(dst + t * YY + base16 + tid, v);
            else                     axs(dst + t * HH + base + tid, v);
            hself[t * ROWS + tid] = v;
            sout[tid] = v;
        }
    }
    __syncthreads();

    // ---- partials for next stage's coefficients (own region, write-once) ----
    const int tmax = (MODE == 5) ? ((t + 1 < TT) ? t : -1) : (t - 1);
    if constexpr (MODE == 2) partials16L(hpart, tmax, cw, blk, sout);
    else                     partials32L(hpart, tmax, cw, blk, sout);
    __syncthreads();   // LDS reuse safety for next stage
}

// ---------------------------------------------------------------------------
// Transpose W1..W4 (64x64 tiles), sentinel-prefill handoff buffers, inner_lr.
// grid: 192 blocks of 256
// ---------------------------------------------------------------------------
__global__ __launch_bounds__(256) void k_tr(
    const float* __restrict__ W1, const float* __restrict__ W2,
    const float* __restrict__ W3, const float* __restrict__ W4,
    float* __restrict__ WT1, float* __restrict__ WT2,
    float* __restrict__ WT3, float* __restrict__ WT4,
    const float* __restrict__ loglr, float* __restrict__ out,
    unsigned* __restrict__ hist0, unsigned* __restrict__ cpart0)
{
    const int tid = threadIdx.x;
    int bid = blockIdx.x;
    if (blockIdx.x == 0 && tid == 0) out[2048] = expf(loglr[0]);

    // Sentinel-prefill: histories (851968 words, contiguous) + cpart (393216).
    {
        const int gt = blockIdx.x * 256 + tid;       // 49152 threads
        for (long i = gt; i < 851968; i += 192 * 256) hist0[i] = SENTU;
        for (long i = gt; i < 393216; i += 192 * 256) cpart0[i] = SENTU;
    }

    const float* src; float* dst; int R, C;
    if (bid < 32)       { src = W1; dst = WT1; R = 512; C = 256; }
    else if (bid < 96)  { src = W2; dst = WT2; R = 512; C = 512; bid -= 32; }
    else if (bid < 160) { src = W3; dst = WT3; R = 512; C = 512; bid -= 96; }
    else                { src = W4; dst = WT4; R = 256; C = 512; bid -= 160; }
    const int tilesC = C >> 6;
    const int i0 = (bid / tilesC) * 64, j0 = (bid % tilesC) * 64;

    __shared__ float sm[64][65];
    #pragma unroll
    for (int rep = 0; rep < 16; ++rep) {
        const int flat = rep * 256 + tid;
        const int r = flat >> 6, c = flat & 63;
        sm[r][c] = src[(i0 + r) * C + j0 + c];
    }
    __syncthreads();
    #pragma unroll
    for (int rep = 0; rep < 16; ++rep) {
        const int flat = rep * 256 + tid;
        const int c = flat >> 6, r = flat & 63;
        dst[(j0 + c) * R + i0 + r] = sm[r][c];
    }
}

// ---------------------------------------------------------------------------
// Persistent inner loop, barrier-free (sentinel data-flow). 256 blocks of 256;
// 16 blocks/task, 32 rows/block. Every cross-block word is write-once.
// ---------------------------------------------------------------------------
__global__ __launch_bounds__(256, 1) void k_inner(
    const float* __restrict__ tx, const float* __restrict__ ty, const float* __restrict__ tg,
    const float* __restrict__ b1v, const float* __restrict__ b2v, const float* __restrict__ b3v,
    const float* __restrict__ W2, const float* __restrict__ W3, const float* __restrict__ W4,
    const float* __restrict__ WT1, const float* __restrict__ WT2, const float* __restrict__ WT3,
    const float* __restrict__ WT4, const float* __restrict__ loglr,
    float* __restrict__ H1, float* __restrict__ H2, float* __restrict__ HG,
    float* __restrict__ D1, float* __restrict__ D2, float* __restrict__ D3, float* __restrict__ D4,
    float* __restrict__ cpart)
{
    const int tid = threadIdx.x;
    const int lane = tid & 63, w = tid >> 6;
    const int g = blockIdx.x;
    const int b = g >> 4;
    const int blk = ((g & 7) << 1) | ((g >> 3) & 1);   // XCD-local weight rows
    const int base = blk * 32, base16 = blk * 16;
    const float lr = expf(loglr[0]);

    const float* txb = tx + b * (TT * XX);
    const float* tyb = ty + b * (TT * YY);
    const float* tgb = tg + b * (TT * HH);
    float* H1b = H1 + b * (TT * HH);
    float* H2b = H2 + b * (TT * HH);
    float* HGb = HG + b * (TT * HH);
    float* D1b = D1 + b * (TT * HH);
    float* D2b = D2 + b * (TT * HH);
    float* D3b = D3 + b * (TT * HH);
    float* D4b = D4 + b * (TT * YY);
    float* creg = cpart + (long)b * 96 * 256;   // per-task: 96 stage regions

    __shared__ float s_x[16 * 260];  // P0 only
    __shared__ float spz[2176];      // P0 only
    __shared__ __align__(16) float s_v[HH];
    __shared__ float sp[128];
    __shared__ float sout[32];
    __shared__ float s_c[16];
    // Block-private history (own 32/16-row slices), LDS-resident:
    __shared__ float hH1[TT * 32], hH2[TT * 32], hHG[TT * 32];
    __shared__ float hD1[TT * 32], hD2[TT * 32], hD3[TT * 32];
    __shared__ float hD4[TT * 16];
    __shared__ float hZ1[TT * 32];
    __shared__ float sG1[TT * 16];

    const float rb2 = (tid < 32) ? b2v[base + tid] : 0.f;
    const float rb3 = (tid < 32) ? b3v[base + tid] : 0.f;

    // ---------------- P0: Z1base (LDS), G1 (LDS, replicated), H1[0] ----------
    {
        const float4* src4 = (const float4*)txb;   // 1024 float4
        #pragma unroll
        for (int q = 0; q < 4; ++q) {
            const int idx = q * 256 + tid;
            const int tt = idx >> 6, k4 = idx & 63;
            *(float4*)&s_x[tt * 260 + k4 * 4] = src4[idx];
        }
    }
    __syncthreads();
    {
        const int r = tid & 31, j = tid >> 5;
        float acc[16];
        #pragma unroll
        for (int tt = 0; tt < 16; ++tt) acc[tt] = 0.f;
        const float* col = WT1 + (j * 32) * HH + base + r;
        #pragma unroll 4
        for (int kk = 0; kk < 32; ++kk) {
            const float wv = col[kk * HH];
            const int k = j * 32 + kk;
            #pragma unroll
            for (int tt = 0; tt < 16; ++tt) acc[tt] += wv * s_x[tt * 260 + k];
        }
        #pragma unroll
        for (int tt = 0; tt < 16; ++tt) {
            float a = acc[tt] + __shfl_xor(acc[tt], 32);
            if (lane < 32) spz[w * 544 + lane * 17 + tt] = a;
        }
        __syncthreads();
        const int rr = tid & 31, tp = tid >> 5;
        #pragma unroll
        for (int q = 0; q < 2; ++q) {
            const int tt = tp * 2 + q;
            const int row = base + rr;
            float v = spz[rr * 17 + tt] + spz[544 + rr * 17 + tt] +
                      spz[1088 + rr * 17 + tt] + spz[1632 + rr * 17 + tt];
            v += b1v[row];
            hZ1[tt * 32 + rr] = v;
            if (tt == 0) {
                const float h = fmaxf(v, 0.f);
                hH1[rr] = h;
                axs(&H1b[row], h);   // self-announces to F2@t=0 pollers
            }
        }
    }
    {   // Gram matrix, replicated per block
        const int ss = tid >> 4, uu = tid & 15;
        float a = 0.f;
        for (int k = 0; k < 256; ++k) a += s_x[ss * 260 + k] * s_x[uu * 260 + k];
        sG1[ss * 16 + uu] = a + 1.0f;
    }
    __syncthreads();

    // ---------------- Phase 1: 16 SGD steps x 6 stages, barrier-free --------
    int k = 0;
    #pragma unroll 1
    for (int t = 0; t < TT; ++t) {
        do_stage<0>(t, lr, base, base16, blk, WT2 + base, H1b + t * HH,
                    H2b, nullptr, tyb, tgb, rb2,
                    creg + (long)k * 256, creg + (long)(k ? k - 1 : 0) * 256,
                    s_v, sp, sout, s_c, hD2, hH2, hH2, hD1, hZ1, sG1);
        ++k;
        do_stage<1>(t, lr, base, base16, blk, WT3 + base, H2b + t * HH,
                    HGb, nullptr, tyb, tgb, rb3,
                    creg + (long)k * 256, creg + (long)(k - 1) * 256,
                    s_v, sp, sout, s_c, hD3, hHG, hHG, hD1, hZ1, sG1);
        ++k;
        do_stage<2>(t, lr, base, base16, blk, WT4 + base16, HGb + t * HH,
                    D4b, nullptr, tyb, tgb, 0.f,
                    creg + (long)k * 256, creg + (long)(k - 1) * 256,
                    s_v, sp, sout, s_c, hD4, hD4, hD4, hD1, hZ1, sG1);
        ++k;
        do_stage<3>(t, lr, base, base16, blk, W4 + base, D4b + t * YY,
                    D3b, nullptr, tyb, tgb, 0.f,
                    creg + (long)k * 256, creg + (long)(k - 1) * 256,
                    s_v, sp, sout, s_c, hHG, hD3, hD3, hD1, hZ1, sG1);
        ++k;
        do_stage<4>(t, lr, base, base16, blk, W3 + base, D3b + t * HH,
                    D2b, nullptr, tyb, tgb, 0.f,
                    creg + (long)k * 256, creg + (long)(k - 1) * 256,
                    s_v, sp, sout, s_c, hH2, hD2, hD2, hD1, hZ1, sG1);
        ++k;
        do_stage<5>(t, lr, base, base16, blk, W2 + base, D2b + t * HH,
                    D1b, H1b, tyb, tgb, 0.f,
                    creg + (long)k * 256, creg + (long)(k - 1) * 256,
                    s_v, sp, sout, s_c, hH1, hH1, hH1, hD1, hZ1, sG1);
        ++k;
    }
}

// ---------------------------------------------------------------------------
// Phase-2 fused layer, 4 test rows per block, 512 threads.
// GEMM: n-QUAD per thread via float4 weight loads (r = tid&63 -> n = nc*256 +
// r*4 .. +3), 8-way k-split (j = tid>>6, KPG = KE/8). Per 4-k chunk: 4 float4
// weight loads + 4 float4 LDS act reads feed 64 FMAs (1:8 load:FMA, 4x better
// than R15's scalar-n version). 16 accumulators, all statically indexed.
// ---------------------------------------------------------------------------
template <int K, int OUT, bool RELU, bool BIAS, bool PLUSONE>
__device__ __forceinline__ void p2_layer(
    const float* __restrict__ WT,      // [K][OUT]
    const float* __restrict__ bias,    // [OUT] or null
    const float* __restrict__ Dj,      // [16][OUT]  (k_inner output)
    const float* __restrict__ Asrc,    // [16][K]    (k_inner output / input)
    float lr, float* sact, float* sactN, float* sWA)
{
    constexpr int KE = (K + 16 + 63) & ~63;   // 320 / 576
    constexpr int KPG = KE / 8;               // 40 / 72 (multiple of 4)
    constexpr int SAP = K + 4;                // sA pitch (bank spread)
    const int tid = threadIdx.x;

    // ---- stage A rows into LDS (batched coherent 64-bit atomic loads) ----
    float* sA = sWA;   // [16][SAP]
    {
        constexpr int TOT = 16 * (K / 2);     // u64 count: 4096 / 2048
        constexpr int PER = TOT / 512;        // 8 / 4
        u64 tmp[PER];
        #pragma unroll
        for (int q = 0; q < PER; ++q)
            tmp[q] = ald8((const u64*)Asrc + tid + q * 512);
        #pragma unroll
        for (int q = 0; q < PER; ++q) {
            const int idx = tid + q * 512;
            const int s = idx / (K / 2), c = idx - s * (K / 2);
            *(u64*)(sA + s * SAP + c * 2) = tmp[q];
        }
    }
    __syncthreads();

    // ---- ip[s][l] -> sact[l][K+s] = -lr*(A_s . act_l + plus1) ----
    // 16 s x 4 l x 8 q (q-interleaved float4s -> bank spread).
    {
        const int s = tid >> 5, lq = tid & 31;
        const int l = lq >> 3, q = lq & 7;
        const float4* av = (const float4*)(sA + s * SAP);
        const float4* xv = (const float4*)(sact + l * PW);
        float a = 0.f;
        for (int k = 0; k < K / 32; ++k) {
            const float4 u = av[k * 8 + q];
            const float4 x = xv[k * 8 + q];
            a += u.x * x.x + u.y * x.y + u.z * x.z + u.w * x.w;
        }
        a += __shfl_xor(a, 1);
        a += __shfl_xor(a, 2);
        a += __shfl_xor(a, 4);
        if (q == 0) sact[l * PW + K + s] = -lr * (a + (PLUSONE ? 1.f : 0.f));
    }
    __syncthreads();

    // ---- GEMM ----
    float* sP = sWA;   // [8 j][64 r][17] partials (sA dead after ip step)
    const int r = tid & 63, j = tid >> 6;    // j in 0..7
    const float* xb = sact + j * KPG;
    for (int nc = 0; nc < OUT / 256; ++nc) {
        const int nq = nc * 256 + r * 4;     // this thread's n-quad
        float4 ac0 = {0.f, 0.f, 0.f, 0.f};
        float4 ac1 = {0.f, 0.f, 0.f, 0.f};
        float4 ac2 = {0.f, 0.f, 0.f, 0.f};
        float4 ac3 = {0.f, 0.f, 0.f, 0.f};
        if ((j + 1) * KPG <= K) {
            const float* c0 = WT + (long)(j * KPG) * OUT + nq;
            #pragma unroll 2
            for (int kk = 0; kk < KPG; kk += 4) {
                const float4 wa = *(const float4*)&c0[(long)(kk + 0) * OUT];
                const float4 wb = *(const float4*)&c0[(long)(kk + 1) * OUT];
                const float4 wc = *(const float4*)&c0[(long)(kk + 2) * OUT];
                const float4 wd = *(const float4*)&c0[(long)(kk + 3) * OUT];
                const float4 x0 = *(const float4*)&xb[0 * PW + kk];
                const float4 x1 = *(const float4*)&xb[1 * PW + kk];
                const float4 x2 = *(const float4*)&xb[2 * PW + kk];
                const float4 x3 = *(const float4*)&xb[3 * PW + kk];
                ac0.x += wa.x*x0.x; ac0.x += wb.x*x0.y; ac0.x += wc.x*x0.z; ac0.x += wd.x*x0.w;
                ac0.y += wa.y*x0.x; ac0.y += wb.y*x0.y; ac0.y += wc.y*x0.z; ac0.y += wd.y*x0.w;
                ac0.z += wa.z*x0.x; ac0.z += wb.z*x0.y; ac0.z += wc.z*x0.z; ac0.z += wd.z*x0.w;
                ac0.w += wa.w*x0.x; ac0.w += wb.w*x0.y; ac0.w += wc.w*x0.z; ac0.w += wd.w*x0.w;
                ac1.x += wa.x*x1.x; ac1.x += wb.x*x1.y; ac1.x += wc.x*x1.z; ac1.x += wd.x*x1.w;
                ac1.y += wa.y*x1.x; ac1.y += wb.y*x1.y; ac1.y += wc.y*x1.z; ac1.y += wd.y*x1.w;
                ac1.z += wa.z*x1.x; ac1.z += wb.z*x1.y; ac1.z += wc.z*x1.z; ac1.z += wd.z*x1.w;
                ac1.w += wa.w*x1.x; ac1.w += wb.w*x1.y; ac1.w += wc.w*x1.z; ac1.w += wd.w*x1.w;
                ac2.x += wa.x*x2.x; ac2.x += wb.x*x2.y; ac2.x += wc.x*x2.z; ac2.x += wd.x*x2.w;
                ac2.y += wa.y*x2.x; ac2.y += wb.y*x2.y; ac2.y += wc.y*x2.z; ac2.y += wd.y*x2.w;
                ac2.z += wa.z*x2.x; ac2.z += wb.z*x2.y; ac2.z += wc.z*x2.z; ac2.z += wd.z*x2.w;
                ac2.w += wa.w*x2.x; ac2.w += wb.w*x2.y; ac2.w += wc.w*x2.z; ac2.w += wd.w*x2.w;
                ac3.x += wa.x*x3.x; ac3.x += wb.x*x3.y; ac3.x += wc.x*x3.z; ac3.x += wd.x*x3.w;
                ac3.y += wa.y*x3.x; ac3.y += wb.y*x3.y; ac3.y += wc.y*x3.z; ac3.y += wd.y*x3.w;
                ac3.z += wa.z*x3.x; ac3.z += wb.z*x3.y; ac3.z += wc.z*x3.z; ac3.z += wd.z*x3.w;
                ac3.w += wa.w*x3.x; ac3.w += wb.w*x3.y; ac3.w += wc.w*x3.z; ac3.w += wd.w*x3.w;
            }
        } else {
            #pragma unroll 2
            for (int kk = 0; kk < KPG; kk += 4) {
                float4 wa, wb, wc, wd;
                {
                    const int k0 = j * KPG + kk;
                    wa = (k0 + 0 < K) ? *(const float4*)&WT[(long)(k0 + 0) * OUT + nq]
                       : (k0 + 0 < K + 16) ? make_float4(ald(&Dj[(k0 + 0 - K) * OUT + nq]),
                                                         ald(&Dj[(k0 + 0 - K) * OUT + nq + 1]),
                                                         ald(&Dj[(k0 + 0 - K) * OUT + nq + 2]),
                                                         ald(&Dj[(k0 + 0 - K) * OUT + nq + 3]))
                       : make_float4(0.f, 0.f, 0.f, 0.f);
                    wb = (k0 + 1 < K) ? *(const float4*)&WT[(long)(k0 + 1) * OUT + nq]
                       : (k0 + 1 < K + 16) ? make_float4(ald(&Dj[(k0 + 1 - K) * OUT + nq]),
                                                         ald(&Dj[(k0 + 1 - K) * OUT + nq + 1]),
                                                         ald(&Dj[(k0 + 1 - K) * OUT + nq + 2]),
                                                         ald(&Dj[(k0 + 1 - K) * OUT + nq + 3]))
                       : make_float4(0.f, 0.f, 0.f, 0.f);
                    wc = (k0 + 2 < K) ? *(const float4*)&WT[(long)(k0 + 2) * OUT + nq]
                       : (k0 + 2 < K + 16) ? make_float4(ald(&Dj[(k0 + 2 - K) * OUT + nq]),
                                                         ald(&Dj[(k0 + 2 - K) * OUT + nq + 1]),
                                                         ald(&Dj[(k0 + 2 - K) * OUT + nq + 2]),
                                                         ald(&Dj[(k0 + 2 - K) * OUT + nq + 3]))
                       : make_float4(0.f, 0.f, 0.f, 0.f);
                    wd = (k0 + 3 < K) ? *(const float4*)&WT[(long)(k0 + 3) * OUT + nq]
                       : (k0 + 3 < K + 16) ? make_float4(ald(&Dj[(k0 + 3 - K) * OUT + nq]),
                                                         ald(&Dj[(k0 + 3 - K) * OUT + nq + 1]),
                                                         ald(&Dj[(k0 + 3 - K) * OUT + nq + 2]),
                                                         ald(&Dj[(k0 + 3 - K) * OUT + nq + 3]))
                       : make_float4(0.f, 0.f, 0.f, 0.f);
                }
                const float4 x0 = *(const float4*)&xb[0 * PW + kk];
                const float4 x1 = *(const float4*)&xb[1 * PW + kk];
                const float4 x2 = *(const float4*)&xb[2 * PW + kk];
                const float4 x3 = *(const float4*)&xb[3 * PW + kk];
                ac0.x += wa.x*x0.x; ac0.x += wb.x*x0.y; ac0.x += wc.x*x0.z; ac0.x += wd.x*x0.w;
                ac0.y += wa.y*x0.x; ac0.y += wb.y*x0.y; ac0.y += wc.y*x0.z; ac0.y += wd.y*x0.w;
                ac0.z += wa.z*x0.x; ac0.z += wb.z*x0.y; ac0.z += wc.z*x0.z; ac0.z += wd.z*x0.w;
                ac0.w += wa.w*x0.x; ac0.w += wb.w*x0.y; ac0.w += wc.w*x0.z; ac0.w += wd.w*x0.w;
                ac1.x += wa.x*x1.x; ac1.x += wb.x*x1.y; ac1.x += wc.x*x1.z; ac1.x += wd.x*x1.w;
                ac1.y += wa.y*x1.x; ac1.y += wb.y*x1.y; ac1.y += wc.y*x1.z; ac1.y += wd.y*x1.w;
                ac1.z += wa.z*x1.x; ac1.z += wb.z*x1.y; ac1.z += wc.z*x1.z; ac1.z += wd.z*x1.w;
                ac1.w += wa.w*x1.x; ac1.w += wb.w*x1.y; ac1.w += wc.w*x1.z; ac1.w += wd.w*x1.w;
                ac2.x += wa.x*x2.x; ac2.x += wb.x*x2.y; ac2.x += wc.x*x2.z; ac2.x += wd.x*x2.w;
                ac2.y += wa.y*x2.x; ac2.y += wb.y*x2.y; ac2.y += wc.y*x2.z; ac2.y += wd.y*x2.w;
                ac2.z += wa.z*x2.x; ac2.z += wb.z*x2.y; ac2.z += wc.z*x2.z; ac2.z += wd.z*x2.w;
                ac2.w += wa.w*x2.x; ac2.w += wb.w*x2.y; ac2.w += wc.w*x2.z; ac2.w += wd.w*x2.w;
                ac3.x += wa.x*x3.x; ac3.x += wb.x*x3.y; ac3.x += wc.x*x3.z; ac3.x += wd.x*x3.w;
                ac3.y += wa.y*x3.x; ac3.y += wb.y*x3.y; ac3.y += wc.y*x3.z; ac3.y += wd.y*x3.w;
                ac3.z += wa.z*x3.x; ac3.z += wb.z*x3.y; ac3.z += wc.z*x3.z; ac3.z += wd.z*x3.w;
                ac3.w += wa.w*x3.x; ac3.w += wb.w*x3.y; ac3.w += wc.w*x3.z; ac3.w += wd.w*x3.w;
            }
        }
        __syncthreads();   // sP region free (vs sA / previous reduce reads)
        {
            float* row = sP + (j * 64 + r) * 17;
            row[0]  = ac0.x; row[1]  = ac0.y; row[2]  = ac0.z; row[3]  = ac0.w;
            row[4]  = ac1.x; row[5]  = ac1.y; row[6]  = ac1.z; row[7]  = ac1.w;
            row[8]  = ac2.x; row[9]  = ac2.y; row[10] = ac2.z; row[11] = ac2.w;
            row[12] = ac3.x; row[13] = ac3.y; row[14] = ac3.z; row[15] = ac3.w;
        }
        __syncthreads();
        {   // 8-way reduce: 2 outputs per thread (256 n x 4 l = 1024)
            #pragma unroll
            for (int e = 0; e < 2; ++e) {
                const int o = tid * 2 + e;
                const int nn = o >> 2, ll = o & 3;       // nn 0..255, ll 0..3
                const int rq = nn >> 2, cq = nn & 3;     // quad, component
                const int off = (ll << 2) + cq;          // ll*4 + c
                float v = 0.f;
                #pragma unroll
                for (int q = 0; q < 8; ++q)
                    v += sP[(q * 64 + rq) * 17 + off];
                const int n = nc * 256 + nn;
                if (BIAS) v += bias[n];
                if (RELU) v = fmaxf(v, 0.f);
                sactN[ll * PW + n] = v;
            }
        }
    }
    __syncthreads();
    // zero-pad cols [OUT+16, PW) of the output for the next consumer
    constexpr int ZC = PW - (OUT + 16);
    for (int f = tid; f < 4 * ZC; f += 512) {
        const int l = f / ZC, c = f - l * ZC;
        sactN[l * PW + OUT + 16 + c] = 0.f;
    }
    __syncthreads();
}

// ---------------------------------------------------------------------------
// Phase-2: test forward + loss, fully block-local. grid 512 blocks of 512:
// block = (task b, 4 test rows) -> 2 blocks/CU (4 waves/SIMD). LDS 53.6 KB.
// ---------------------------------------------------------------------------
__global__ __launch_bounds__(512, 4) void k_p2(
    const float* __restrict__ tx, const float* __restrict__ tex,
    const float* __restrict__ tey, const float* __restrict__ teg,
    const float* __restrict__ b1v, const float* __restrict__ b2v,
    const float* __restrict__ b3v,
    const float* __restrict__ WT1, const float* __restrict__ WT2,
    const float* __restrict__ WT3, const float* __restrict__ WT4,
    const float* __restrict__ H1, const float* __restrict__ H2,
    const float* __restrict__ HG,
    const float* __restrict__ D1, const float* __restrict__ D2,
    const float* __restrict__ D3, const float* __restrict__ D4,
    const float* __restrict__ loglr, float* __restrict__ outp)
{
    const int tid = threadIdx.x;
    const int b = blockIdx.x >> 5;
    const int l0 = (blockIdx.x & 31) * 4;
    const float lr = expf(loglr[0]);

    __shared__ __align__(16) float pool[13408];   // 53.6 KB
    float* a0  = pool;            // act buffers [4][PW]
    float* a1  = pool + 2352;     // 4*588
    float* sWA = pool + 4704;     // scratch: sA [16][K+4] / sP [8][64][17]

    const float* txb = tx + b * (TT * XX);
    const float* H1b = H1 + b * (TT * HH);
    const float* H2b = H2 + b * (TT * HH);
    const float* HGb = HG + b * (TT * HH);
    const float* D1b = D1 + b * (TT * HH);
    const float* D2b = D2 + b * (TT * HH);
    const float* D3b = D3 + b * (TT * HH);
    const float* D4b = D4 + b * (TT * YY);

    // stage tex rows (zero-padded to PW)
    for (int f = tid; f < 4 * PW; f += 512) {
        const int l = f / PW, c = f - l * PW;
        a0[f] = (c < XX) ? tex[((long)b * LL + l0 + l) * XX + c] : 0.f;
    }
    __syncthreads();

    p2_layer<XX, HH, true, true, true>(WT1, b1v, D1b, txb, lr, a0, a1, sWA);
    p2_layer<HH, HH, true, true, true>(WT2, b2v, D2b, H1b, lr, a1, a0, sWA);
    p2_layer<HH, HH, true, true, true>(WT3, b3v, D3b, H2b, lr, a0, a1, sWA);

    // gate act3 with test_gate
    for (int f = tid; f < 4 * HH; f += 512) {
        const int l = f >> 9, k = f & 511;
        a1[l * PW + k] *= teg[((long)b * LL + l0 + l) * HH + k];
    }
    __syncthreads();

    p2_layer<HH, YY, false, false, false>(WT4, nullptr, D4b, HGb, lr, a1, a0, sWA);

    // logits out
    for (int f = tid; f < 4 * YY; f += 512) {
        const int l = f >> 8, y = f & 255;
        outp[4097 + ((long)(b * LL + l0 + l)) * YY + y] = a0[l * PW + y];
    }
    // loss + evaluation (first 128 threads: 4 l x 32 lanes)
    if (tid < 128) {
        const int l = tid >> 5, kk = tid & 31;
        float a = 0.f;
        #pragma unroll
        for (int jj = 0; jj < 8; ++jj) {
            const int y = kk * 8 + jj;
            const float d = a0[l * PW + y] -
                            tey[((long)b * LL + l0 + l) * YY + y];
            a += d * d;
        }
        a += __shfl_xor(a, 1);
        a += __shfl_xor(a, 2);
        a += __shfl_xor(a, 4);
        a += __shfl_xor(a, 8);
        a += __shfl_xor(a, 16);
        if (kk == 0) {
            const float v = a * (1.0f / YY);
            const int idx = b * LL + l0 + l;
            outp[idx] = v;
            outp[2049 + idx] = v;
        }
    }
}

// ---------------------------------------------------------------------------
extern "C" void kernel_launch(void* const* d_in, const int* in_sizes, int n_in,
                              void* d_out, int out_size, void* d_ws, size_t ws_size,
                              hipStream_t stream)
{
    const float* tx    = (const float*)d_in[0];   // train_x  [B][T][X]
    const float* ty    = (const float*)d_in[1];   // train_y  [B][T][Y]
    const float* tex   = (const float*)d_in[2];   // test_x   [B][L][X]
    const float* tey   = (const float*)d_in[3];   // test_y   [B][L][Y]
    const float* tg    = (const float*)d_in[4];   // train_gate [B][T][H]
    const float* teg   = (const float*)d_in[5];   // test_gate  [B][L][H]
    const float* W1    = (const float*)d_in[6];
    const float* b1    = (const float*)d_in[7];
    const float* W2    = (const float*)d_in[8];
    const float* b2    = (const float*)d_in[9];
    const float* W3    = (const float*)d_in[10];
    const float* b3    = (const float*)d_in[11];
    const float* W4    = (const float*)d_in[12];
    const float* loglr = (const float*)d_in[13];

    float* out = (float*)d_out;
    float* ws  = (float*)d_ws;

    // workspace layout (floats). H1..D4 are contiguous (851968 words) and
    // sentinel-prefilled by k_tr. cpart lives in the unused ActB region.
    float* H1     = ws + 135168;        // 131072
    float* H2     = ws + 266240;        // 131072
    float* HG     = ws + 397312;        // 131072
    float* D1     = ws + 528384;        // 131072
    float* D2     = ws + 659456;        // 131072
    float* D3     = ws + 790528;        // 131072
    float* D4     = ws + 921600;        // 65536
    float* ActA   = ws + 1024000;       // holds WT1..WT4
    float* WT1    = ActA;               // [256][512] = 131072
    float* WT2    = ActA + 131072;      // [512][512] = 262144
    float* WT3    = ActA + 393216;      // [512][512] = 262144
    float* WT4    = ActA + 655360;      // [512][256] = 131072
    float* cpart  = ws + 2072576;       // 16 tasks x 96 stages x 256 = 393216

    // Transpose weights + sentinel-prefill handoff buffers + inner_lr.
    k_tr<<<192, 256, 0, stream>>>(W1, W2, W3, W4, WT1, WT2, WT3, WT4, loglr,
                                  out, (unsigned*)H1, (unsigned*)cpart);

    // 16-step MAML inner loop (persistent, barrier-free sentinel data-flow).
    k_inner<<<TB * 16, 256, 0, stream>>>(tx, ty, tg, b1, b2, b3, W2, W3, W4,
                                         WT1, WT2, WT3, WT4, loglr,
                                         H1, H2, HG, D1, D2, D3, D4, cpart);

    // Phase 2: test-set forward + loss; 512 blocks of 512 (2 blocks/CU).
    k_p2<<<TB * 32, 512, 0, stream>>>(tx, tex, tey, teg, b1, b2, b3,
                                      WT1, WT2, WT3, WT4,
                                      H1, H2, HG, D1, D2, D3, D4,
                                      loglr, out);
}